// Round 6
// baseline (893.846 us; speedup 1.0000x reference)
//
#include <hip/hip_runtime.h>

// RowAreaAttention split pipeline (round 6):
//  K0 prep_w: f32->f16 weights only (w_qkv, w_proj)
//  K1 gemm_a32: QKV = x(f32,reg-staged) @ wq16^T (65536 x 2304 x 768) -> qkv f16
//     2-phase 128x128/BK=32 (round-3 proven structure, 703 TF)
//  K2 attn64: per (group,head) 64x64 attention, O written in-place into Q slot
//  K3 gemm_bt: out = Qslot @ wp16^T + bias (65536 x 768 x 768) -> f32

#define SCALE 0.125f

typedef _Float16 h16;
typedef h16   half8 __attribute__((ext_vector_type(8)));
typedef float f32x4 __attribute__((ext_vector_type(4)));

typedef const __attribute__((address_space(1))) unsigned int ga_u32;
typedef __attribute__((address_space(3))) unsigned int ls_u32;

// ---------------------------------------------------------------- K0: prep
__device__ __forceinline__ void cvt8(const float* __restrict__ s,
                                     h16* __restrict__ d, int i) {
  const float4 a = ((const float4*)s)[2 * i];
  const float4 b = ((const float4*)s)[2 * i + 1];
  half8 r;
  r[0] = (h16)a.x; r[1] = (h16)a.y; r[2] = (h16)a.z; r[3] = (h16)a.w;
  r[4] = (h16)b.x; r[5] = (h16)b.y; r[6] = (h16)b.z; r[7] = (h16)b.w;
  ((half8*)d)[i] = r;
}

__global__ void prep_w_only(const float* __restrict__ wq, const float* __restrict__ wp,
                            h16* __restrict__ wq16, h16* __restrict__ wp16) {
  const int stride = gridDim.x * blockDim.x;
  const int t0 = blockIdx.x * blockDim.x + threadIdx.x;
  for (int i = t0; i < 221184; i += stride) cvt8(wq, wq16, i);   // 2304*768
  for (int i = t0; i < 73728;  i += stride) cvt8(wp, wp16, i);   // 768*768
}

// -------------------------------------------- K1: gemm_a32 (A f32 reg-staged)
// C(M x 2304) f16 = A32(M x 768 f32) @ B(2304 x 768 f16)^T
// 128x128 tile, BK=32, 24 K-steps, 4 waves, double-buffered.
// A: global float4 loads (issued early) -> cvt -> ds_write_b128 (after vmcnt(0)).
//    Unswizzled [128][32] h16: at 64B row stride, ds_read_b128 frag reads are
//    inherently bank-balanced (slot = 4*(row&1)+kg, 8 lanes/slot = b128 floor).
// B: global_load_lds w/ round-3 swizzle (measured 0 conflicts).
__global__ __launch_bounds__(256)
void gemm_a32(const float* __restrict__ A32,
              const h16* __restrict__ B,
              h16* __restrict__ C, int ldc,
              int ntiles) {
  __shared__ h16 As[2][4096];
  __shared__ h16 Bs[2][4096];

  const int nwg = gridDim.x;
  const int bid = blockIdx.x;
  const int wg  = (bid & 7) * (nwg >> 3) + (bid >> 3);   // XCD-chunked swizzle
  const int mt = wg / ntiles, nt = wg - mt * ntiles;
  const int m0 = mt * 128, n0 = nt * 128;

  const int tid  = threadIdx.x;
  const int lane = tid & 63;
  const int wv   = tid >> 6;
  const int l16  = lane & 15;
  const int kg   = lane >> 4;

  // ---- B staging (gload_lds, swizzled; 2 chunks/thread)
  const h16* pb[2];
  int lob[2];
  #pragma unroll
  for (int i = 0; i < 2; ++i) {
    const int row = wv * 32 + i * 16 + (lane >> 2);
    const int cg  = (lane & 3) ^ ((row >> 1) & 3);
    pb[i] = B + (size_t)(n0 + row) * 768 + cg * 8;
    lob[i] = wv * 1024 + i * 512;
  }
#define STAGE_B(bf, koff)                                                      \
  do {                                                                         \
    __builtin_amdgcn_global_load_lds((ga_u32*)(const void*)(pb[0] + (koff)),   \
                                     (ls_u32*)(void*)&Bs[bf][lob[0]], 16, 0, 0);\
    __builtin_amdgcn_global_load_lds((ga_u32*)(const void*)(pb[1] + (koff)),   \
                                     (ls_u32*)(void*)&Bs[bf][lob[1]], 16, 0, 0);\
  } while (0)

  // ---- A staging (reg-staged f32): thread covers 8-f32 chunks c8={tid, tid+256}
  const int ra0 = tid >> 2, qa0 = tid & 3;   // row 0..63, quarter 0..3
  const int ra1 = ra0 + 64;
  const float* pA0 = A32 + (size_t)(m0 + ra0) * 768 + qa0 * 8;
  const float* pA1 = A32 + (size_t)(m0 + ra1) * 768 + qa0 * 8;
  const int wa0 = ra0 * 32 + qa0 * 8;        // h16 LDS offsets
  const int wa1 = ra1 * 32 + qa0 * 8;

  // ---- fragment read offsets (h16 units)
  const int s   = (l16 >> 1) & 3;
  const int wr  = wv >> 1, wc = wv & 1;
  const int ofA = (wr * 64 + l16) * 32 + kg * 8;            // unswizzled
  const int ofB = (wc * 64 + l16) * 32 + ((kg ^ s) * 8);    // swizzled

  f32x4 acc[4][4];
  #pragma unroll
  for (int mi = 0; mi < 4; ++mi)
    #pragma unroll
    for (int ni = 0; ni < 4; ++ni)
      acc[mi][ni] = (f32x4){0.f, 0.f, 0.f, 0.f};

  // ---- prologue: stage tile 0
  {
    const float4 f0 = *(const float4*)(pA0);
    const float4 f1 = *(const float4*)(pA0 + 4);
    const float4 f2 = *(const float4*)(pA1);
    const float4 f3 = *(const float4*)(pA1 + 4);
    STAGE_B(0, 0);
    asm volatile("s_waitcnt vmcnt(0)" ::: "memory");
    half8 h0, h1;
    h0[0]=(h16)f0.x; h0[1]=(h16)f0.y; h0[2]=(h16)f0.z; h0[3]=(h16)f0.w;
    h0[4]=(h16)f1.x; h0[5]=(h16)f1.y; h0[6]=(h16)f1.z; h0[7]=(h16)f1.w;
    h1[0]=(h16)f2.x; h1[1]=(h16)f2.y; h1[2]=(h16)f2.z; h1[3]=(h16)f2.w;
    h1[4]=(h16)f3.x; h1[5]=(h16)f3.y; h1[6]=(h16)f3.z; h1[7]=(h16)f3.w;
    *(half8*)&As[0][wa0] = h0;
    *(half8*)&As[0][wa1] = h1;
  }
  __syncthreads();

  int cur = 0;
  for (int t = 0; t < 24; ++t) {
    float4 f0, f1, f2, f3;
    if (t < 23) {
      const int koff = (t + 1) * 32;
      f0 = *(const float4*)(pA0 + koff);
      f1 = *(const float4*)(pA0 + koff + 4);
      f2 = *(const float4*)(pA1 + koff);
      f3 = *(const float4*)(pA1 + koff + 4);
      STAGE_B(cur ^ 1, koff);
    }

    half8 af[4], bf8[4];
    #pragma unroll
    for (int mi = 0; mi < 4; ++mi) af[mi]  = *(const half8*)&As[cur][ofA + mi * 512];
    #pragma unroll
    for (int ni = 0; ni < 4; ++ni) bf8[ni] = *(const half8*)&Bs[cur][ofB + ni * 512];
    #pragma unroll
    for (int mi = 0; mi < 4; ++mi)
      #pragma unroll
      for (int ni = 0; ni < 4; ++ni)
        acc[mi][ni] = __builtin_amdgcn_mfma_f32_16x16x32_f16(af[mi], bf8[ni], acc[mi][ni], 0, 0, 0);

    if (t < 23) {
      asm volatile("s_waitcnt vmcnt(0)" ::: "memory");
      half8 h0, h1;
      h0[0]=(h16)f0.x; h0[1]=(h16)f0.y; h0[2]=(h16)f0.z; h0[3]=(h16)f0.w;
      h0[4]=(h16)f1.x; h0[5]=(h16)f1.y; h0[6]=(h16)f1.z; h0[7]=(h16)f1.w;
      h1[0]=(h16)f2.x; h1[1]=(h16)f2.y; h1[2]=(h16)f2.z; h1[3]=(h16)f2.w;
      h1[4]=(h16)f3.x; h1[5]=(h16)f3.y; h1[6]=(h16)f3.z; h1[7]=(h16)f3.w;
      *(half8*)&As[cur ^ 1][wa0] = h0;
      *(half8*)&As[cur ^ 1][wa1] = h1;
    }
    __syncthreads();
    cur ^= 1;
  }
#undef STAGE_B

  #pragma unroll
  for (int mi = 0; mi < 4; ++mi) {
    #pragma unroll
    for (int ni = 0; ni < 4; ++ni) {
      const int col = n0 + wc * 64 + ni * 16 + l16;
      #pragma unroll
      for (int j = 0; j < 4; ++j) {
        const int row = m0 + wr * 64 + mi * 16 + kg * 4 + j;
        C[(size_t)row * ldc + col] = (h16)acc[mi][ni][j];
      }
    }
  }
}

// ------------------------------------------------------- K3: gemm_bt (round-3)
// C(M x N) = A(M x 768 f16, lda) @ B(N x 768 f16)^T [+ bias], 128x128, BK=32.
template <bool BIAS, typename OutT>
__global__ void gemm_bt(const h16* __restrict__ A, int lda,
                        const h16* __restrict__ B,
                        const float* __restrict__ bias,
                        OutT* __restrict__ C, int ldc,
                        int ntiles) {
  __shared__ h16 As[2][4096];
  __shared__ h16 Bs[2][4096];

  const int nwg = gridDim.x;
  const int bid = blockIdx.x;
  const int wg  = (bid & 7) * (nwg >> 3) + (bid >> 3);
  const int mt = wg / ntiles, nt = wg - mt * ntiles;
  const int m0 = mt * 128, n0 = nt * 128;

  const int tid  = threadIdx.x;
  const int lane = tid & 63;
  const int wv   = tid >> 6;
  const int l16  = lane & 15;
  const int kg   = lane >> 4;

  const h16* pa[2];
  const h16* pb[2];
  int lo[2];
  #pragma unroll
  for (int i = 0; i < 2; ++i) {
    const int row = wv * 32 + i * 16 + (lane >> 2);
    const int cg  = (lane & 3) ^ ((row >> 1) & 3);
    pa[i] = A + (size_t)(m0 + row) * lda + cg * 8;
    pb[i] = B + (size_t)(n0 + row) * 768 + cg * 8;
    lo[i] = wv * 1024 + i * 512;
  }

#define STAGE(bf, koff)                                                        \
  do {                                                                         \
    __builtin_amdgcn_global_load_lds((ga_u32*)(const void*)(pa[0] + (koff)),   \
                                     (ls_u32*)(void*)&As[bf][lo[0]], 16, 0, 0);\
    __builtin_amdgcn_global_load_lds((ga_u32*)(const void*)(pb[0] + (koff)),   \
                                     (ls_u32*)(void*)&Bs[bf][lo[0]], 16, 0, 0);\
    __builtin_amdgcn_global_load_lds((ga_u32*)(const void*)(pa[1] + (koff)),   \
                                     (ls_u32*)(void*)&As[bf][lo[1]], 16, 0, 0);\
    __builtin_amdgcn_global_load_lds((ga_u32*)(const void*)(pb[1] + (koff)),   \
                                     (ls_u32*)(void*)&Bs[bf][lo[1]], 16, 0, 0);\
  } while (0)

  const int s   = (l16 >> 1) & 3;
  const int wr  = wv >> 1, wc = wv & 1;
  const int ofA = (wr * 64 + l16) * 32 + ((kg ^ s) * 8);
  const int ofB = (wc * 64 + l16) * 32 + ((kg ^ s) * 8);

  f32x4 acc[4][4];
  #pragma unroll
  for (int mi = 0; mi < 4; ++mi)
    #pragma unroll
    for (int ni = 0; ni < 4; ++ni)
      acc[mi][ni] = (f32x4){0.f, 0.f, 0.f, 0.f};

  STAGE(0, 0);
  asm volatile("s_waitcnt vmcnt(0)" ::: "memory");
  __syncthreads();

  int cur = 0;
  for (int t = 0; t < 24; ++t) {
    if (t < 23) STAGE(cur ^ 1, (t + 1) * 32);
    half8 af[4], bf8[4];
    #pragma unroll
    for (int mi = 0; mi < 4; ++mi) af[mi]  = *(const half8*)&As[cur][ofA + mi * 512];
    #pragma unroll
    for (int ni = 0; ni < 4; ++ni) bf8[ni] = *(const half8*)&Bs[cur][ofB + ni * 512];
    #pragma unroll
    for (int mi = 0; mi < 4; ++mi)
      #pragma unroll
      for (int ni = 0; ni < 4; ++ni)
        acc[mi][ni] = __builtin_amdgcn_mfma_f32_16x16x32_f16(af[mi], bf8[ni], acc[mi][ni], 0, 0, 0);
    asm volatile("s_waitcnt vmcnt(0)" ::: "memory");
    __syncthreads();
    cur ^= 1;
  }
#undef STAGE

  float bv[4];
  if (BIAS) {
    #pragma unroll
    for (int ni = 0; ni < 4; ++ni) bv[ni] = bias[n0 + wc * 64 + ni * 16 + l16];
  }
  #pragma unroll
  for (int mi = 0; mi < 4; ++mi) {
    #pragma unroll
    for (int ni = 0; ni < 4; ++ni) {
      const int col = n0 + wc * 64 + ni * 16 + l16;
      #pragma unroll
      for (int j = 0; j < 4; ++j) {
        const int row = m0 + wr * 64 + mi * 16 + kg * 4 + j;
        if (BIAS) C[(size_t)row * ldc + col] = (OutT)(acc[mi][ni][j] + bv[ni]);
        else      C[(size_t)row * ldc + col] = (OutT)acc[mi][ni][j];
      }
    }
  }
}

// ---------------------------------------------------------------- K2: attn
// One WG (4 waves) per (group, head). qkv row-major [65536][2304] f16.
// Q slice at col h*64, K at +768, V at +1536. O overwrites the Q slice.
__global__ void attn64(h16* __restrict__ qkv) {
  __shared__ h16 vt[64][72];   // V^T [dim][token]
  __shared__ h16 ps[64][72];   // P, then O

  const int bid = blockIdx.x;
  const int g = bid / 12, h = bid - g * 12;
  const int tid = threadIdx.x, lane = tid & 63, wv = tid >> 6;
  const int l16 = lane & 15, kg = lane >> 4;

  h16* qp = qkv + (size_t)g * 64 * 2304 + h * 64;
  const h16* kp = qp + 768;
  const h16* vp = qp + 1536;

  // stage V^T
  #pragma unroll
  for (int c = tid; c < 512; c += 256) {
    const int tok = c >> 3, d0 = (c & 7) * 8;
    const half8 v = *(const half8*)(vp + (size_t)tok * 2304 + d0);
    #pragma unroll
    for (int u = 0; u < 8; ++u) vt[d0 + u][tok] = v[u];
  }

  // S = Q K^T for rows [wv*16, wv*16+16)
  const int qrow = wv * 16 + l16;
  half8 qa[2];
  #pragma unroll
  for (int kb = 0; kb < 2; ++kb)
    qa[kb] = *(const half8*)(qp + (size_t)qrow * 2304 + kb * 32 + kg * 8);

  f32x4 sacc[4];
  #pragma unroll
  for (int cb = 0; cb < 4; ++cb) sacc[cb] = (f32x4){0.f, 0.f, 0.f, 0.f};
  #pragma unroll
  for (int cb = 0; cb < 4; ++cb)
    #pragma unroll
    for (int kb = 0; kb < 2; ++kb) {
      const half8 kf = *(const half8*)(kp + (size_t)(cb * 16 + l16) * 2304 + kb * 32 + kg * 8);
      sacc[cb] = __builtin_amdgcn_mfma_f32_16x16x32_f16(qa[kb], kf, sacc[cb], 0, 0, 0);
    }

  // max-free softmax (|S*scale| << 88): rows wv*16 + kg*4 + j
  float e[4][4], rs[4];
  #pragma unroll
  for (int j = 0; j < 4; ++j) {
    float t = 0.f;
    #pragma unroll
    for (int cb = 0; cb < 4; ++cb) { e[cb][j] = __expf(sacc[cb][j] * SCALE); t += e[cb][j]; }
    rs[j] = t;
  }
  #pragma unroll
  for (int m = 1; m < 16; m <<= 1)
    #pragma unroll
    for (int j = 0; j < 4; ++j) rs[j] += __shfl_xor(rs[j], m);
  #pragma unroll
  for (int j = 0; j < 4; ++j) rs[j] = __fdividef(1.0f, rs[j]);

  const int prow = wv * 16 + kg * 4;
  #pragma unroll
  for (int cb = 0; cb < 4; ++cb)
    #pragma unroll
    for (int j = 0; j < 4; ++j)
      ps[prow + j][cb * 16 + l16] = (h16)(e[cb][j] * rs[j]);

  __syncthreads();   // vt staged by all waves

  // O = P V
  half8 pa[2];
  #pragma unroll
  for (int kb = 0; kb < 2; ++kb)
    pa[kb] = *(const half8*)&ps[wv * 16 + l16][kb * 32 + kg * 8];
  f32x4 oacc[4];
  #pragma unroll
  for (int cb = 0; cb < 4; ++cb) oacc[cb] = (f32x4){0.f, 0.f, 0.f, 0.f};
  #pragma unroll
  for (int cb = 0; cb < 4; ++cb)
    #pragma unroll
    for (int kb = 0; kb < 2; ++kb) {
      const half8 vf = *(const half8*)&vt[cb * 16 + l16][kb * 32 + kg * 8];
      oacc[cb] = __builtin_amdgcn_mfma_f32_16x16x32_f16(pa[kb], vf, oacc[cb], 0, 0, 0);
    }

  // O -> ps, then vectorized in-place store to Q slot
  #pragma unroll
  for (int cb = 0; cb < 4; ++cb)
    #pragma unroll
    for (int j = 0; j < 4; ++j)
      ps[prow + j][cb * 16 + l16] = (h16)oacc[cb][j];
  __syncthreads();
  #pragma unroll
  for (int c = tid; c < 512; c += 256) {
    const int tok = c >> 3, d0 = (c & 7) * 8;
    *(half8*)(qp + (size_t)tok * 2304 + d0) = *(const half8*)&ps[tok][d0];
  }
}

// ------------------------------------------- fallback: fused kernel (small ws)
template <typename WT>
__device__ __forceinline__ half8 loadw8(const WT* p);
template <>
__device__ __forceinline__ half8 loadw8<h16>(const h16* p) { return *(const half8*)p; }
template <>
__device__ __forceinline__ half8 loadw8<float>(const float* p) {
  const float4 a = *(const float4*)p;
  const float4 b = *(const float4*)(p + 4);
  half8 r;
  r[0] = (h16)a.x; r[1] = (h16)a.y; r[2] = (h16)a.z; r[3] = (h16)a.w;
  r[4] = (h16)b.x; r[5] = (h16)b.y; r[6] = (h16)b.z; r[7] = (h16)b.w;
  return r;
}

template <typename WT>
__launch_bounds__(512, 2)
__global__ void fused_fb(const float* __restrict__ x,
                         const WT* __restrict__ wq,
                         const WT* __restrict__ wp,
                         const float* __restrict__ bias,
                         float* __restrict__ out) {
  __shared__ h16   xs[64][776];
  __shared__ h16   qs[64][72];
  __shared__ h16   ks[64][72];
  __shared__ h16   vt[64][72];
  __shared__ float sS[64][68];

  const int g = blockIdx.x, tid = threadIdx.x;
  const int wv = tid >> 6, lane = tid & 63, l16 = lane & 15, kg = lane >> 4;

  const float* xg = x + (size_t)g * (64 * 768);
  #pragma unroll
  for (int i = 0; i < 24; ++i) {
    const int idx = tid + i * 512;
    const int row = idx / 192;
    const int c4  = (idx - row * 192) * 4;
    const float4 v = ((const float4*)xg)[idx];
    h16* p = &xs[row][c4];
    p[0] = (h16)v.x; p[1] = (h16)v.y; p[2] = (h16)v.z; p[3] = (h16)v.w;
  }

  f32x4 acc[4][6];
  #pragma unroll
  for (int a = 0; a < 4; ++a)
    #pragma unroll
    for (int b = 0; b < 6; ++b) acc[a][b] = (f32x4){0.f, 0.f, 0.f, 0.f};

  float bcol[6];
  #pragma unroll
  for (int cb = 0; cb < 6; ++cb) bcol[cb] = bias[wv * 96 + cb * 16 + l16];

  const int r0 = (wv & 1) * 32, c0 = (wv >> 1) * 48;
  const int rS = (wv >> 1) * 16, cS = (wv & 1) * 32;
  __syncthreads();

  for (int h = 0; h < 12; ++h) {
    f32x4 facc[2][3];
    #pragma unroll
    for (int a = 0; a < 2; ++a)
      #pragma unroll
      for (int b = 0; b < 3; ++b) facc[a][b] = (f32x4){0.f, 0.f, 0.f, 0.f};
    int wrow[3];
    #pragma unroll
    for (int cb = 0; cb < 3; ++cb) {
      const int n = c0 + cb * 16;
      wrow[cb] = (n >> 6) * 768 + h * 64 + (n & 63) + l16;
    }
    for (int k0 = 0; k0 < 768; k0 += 32) {
      const half8 a0 = *(const half8*)&xs[r0 + l16][k0 + kg * 8];
      const half8 a1 = *(const half8*)&xs[r0 + 16 + l16][k0 + kg * 8];
      #pragma unroll
      for (int cb = 0; cb < 3; ++cb) {
        const half8 b = loadw8<WT>(wq + (size_t)wrow[cb] * 768 + k0 + kg * 8);
        facc[0][cb] = __builtin_amdgcn_mfma_f32_16x16x32_f16(a0, b, facc[0][cb], 0, 0, 0);
        facc[1][cb] = __builtin_amdgcn_mfma_f32_16x16x32_f16(a1, b, facc[1][cb], 0, 0, 0);
      }
    }
    #pragma unroll
    for (int rb = 0; rb < 2; ++rb)
      #pragma unroll
      for (int cb = 0; cb < 3; ++cb) {
        const int col = c0 + cb * 16 + l16;
        const int rowb = r0 + rb * 16 + kg * 4;
        if (col < 64) {
          #pragma unroll
          for (int j = 0; j < 4; ++j) qs[rowb + j][col] = (h16)facc[rb][cb][j];
        } else if (col < 128) {
          #pragma unroll
          for (int j = 0; j < 4; ++j) ks[rowb + j][col - 64] = (h16)facc[rb][cb][j];
        } else {
          #pragma unroll
          for (int j = 0; j < 4; ++j) vt[col - 128][rowb + j] = (h16)facc[rb][cb][j];
        }
      }
    __syncthreads();

    f32x4 sacc[2];
    sacc[0] = (f32x4){0.f, 0.f, 0.f, 0.f};
    sacc[1] = (f32x4){0.f, 0.f, 0.f, 0.f};
    #pragma unroll
    for (int k0 = 0; k0 < 64; k0 += 32) {
      const half8 aq = *(const half8*)&qs[rS + l16][k0 + kg * 8];
      const half8 b0 = *(const half8*)&ks[cS + l16][k0 + kg * 8];
      const half8 b1 = *(const half8*)&ks[cS + 16 + l16][k0 + kg * 8];
      sacc[0] = __builtin_amdgcn_mfma_f32_16x16x32_f16(aq, b0, sacc[0], 0, 0, 0);
      sacc[1] = __builtin_amdgcn_mfma_f32_16x16x32_f16(aq, b1, sacc[1], 0, 0, 0);
    }
    #pragma unroll
    for (int t = 0; t < 2; ++t)
      #pragma unroll
      for (int j = 0; j < 4; ++j)
        sS[rS + kg * 4 + j][cS + t * 16 + l16] = sacc[t][j] * SCALE;
    __syncthreads();

    {
      const int row = tid >> 3, j0 = (tid & 7) * 8;
      float v0[8];
      #pragma unroll
      for (int i = 0; i < 8; ++i) v0[i] = sS[row][j0 + i];
      float m = v0[0];
      #pragma unroll
      for (int i = 1; i < 8; ++i) m = fmaxf(m, v0[i]);
      m = fmaxf(m, __shfl_xor(m, 1));
      m = fmaxf(m, __shfl_xor(m, 2));
      m = fmaxf(m, __shfl_xor(m, 4));
      float e[8], ssum = 0.f;
      #pragma unroll
      for (int i = 0; i < 8; ++i) { e[i] = __expf(v0[i] - m); ssum += e[i]; }
      ssum += __shfl_xor(ssum, 1);
      ssum += __shfl_xor(ssum, 2);
      ssum += __shfl_xor(ssum, 4);
      const float inv = 1.0f / ssum;
      #pragma unroll
      for (int i = 0; i < 8; ++i) qs[row][j0 + i] = (h16)(e[i] * inv);
    }
    __syncthreads();

    f32x4 oacc[2];
    oacc[0] = (f32x4){0.f, 0.f, 0.f, 0.f};
    oacc[1] = (f32x4){0.f, 0.f, 0.f, 0.f};
    #pragma unroll
    for (int k0 = 0; k0 < 64; k0 += 32) {
      const half8 ap = *(const half8*)&qs[rS + l16][k0 + kg * 8];
      const half8 b0 = *(const half8*)&vt[cS + l16][k0 + kg * 8];
      const half8 b1 = *(const half8*)&vt[cS + 16 + l16][k0 + kg * 8];
      oacc[0] = __builtin_amdgcn_mfma_f32_16x16x32_f16(ap, b0, oacc[0], 0, 0, 0);
      oacc[1] = __builtin_amdgcn_mfma_f32_16x16x32_f16(ap, b1, oacc[1], 0, 0, 0);
    }
    #pragma unroll
    for (int t = 0; t < 2; ++t)
      #pragma unroll
      for (int j = 0; j < 4; ++j)
        ks[rS + kg * 4 + j][cS + t * 16 + l16] = (h16)oacc[t][j];
    __syncthreads();

    #pragma unroll
    for (int k0 = 0; k0 < 64; k0 += 32) {
      half8 ah[4];
      #pragma unroll
      for (int rb = 0; rb < 4; ++rb)
        ah[rb] = *(const half8*)&ks[rb * 16 + l16][k0 + kg * 8];
      #pragma unroll
      for (int cb = 0; cb < 6; ++cb) {
        const int ocol = wv * 96 + cb * 16 + l16;
        const half8 bw = loadw8<WT>(wp + (size_t)ocol * 768 + h * 64 + k0 + kg * 8);
        #pragma unroll
        for (int rb = 0; rb < 4; ++rb)
          acc[rb][cb] = __builtin_amdgcn_mfma_f32_16x16x32_f16(ah[rb], bw, acc[rb][cb], 0, 0, 0);
      }
    }
    __syncthreads();
  }

  float* og = out + (size_t)g * (64 * 768);
  #pragma unroll
  for (int rb = 0; rb < 4; ++rb)
    #pragma unroll
    for (int cb = 0; cb < 6; ++cb) {
      const int col = wv * 96 + cb * 16 + l16;
      #pragma unroll
      for (int j = 0; j < 4; ++j) {
        const int row = rb * 16 + kg * 4 + j;
        og[(size_t)row * 768 + col] = acc[rb][cb][j] + bcol[cb];
      }
    }
}

// ---------------------------------------------------------------- launch
extern "C" void kernel_launch(void* const* d_in, const int* in_sizes, int n_in,
                              void* d_out, int out_size, void* d_ws, size_t ws_size,
                              hipStream_t stream) {
  const float* x     = (const float*)d_in[0];
  const float* wqkv  = (const float*)d_in[1];
  const float* wproj = (const float*)d_in[2];
  const float* bias  = (const float*)d_in[3];
  float* out = (float*)d_out;

  const size_t SZ_WQ  = (size_t)2304 * 768 * sizeof(h16);   //   3.54 MB
  const size_t SZ_WP  = (size_t)768 * 768 * sizeof(h16);    //   1.18 MB
  const size_t SZ_QKV = (size_t)65536 * 2304 * sizeof(h16); // 301.99 MB

  if (ws_size >= SZ_WQ + SZ_WP + SZ_QKV) {
    h16* wq16 = (h16*)d_ws;
    h16* wp16 = (h16*)((char*)d_ws + SZ_WQ);
    h16* qkv  = (h16*)((char*)d_ws + SZ_WQ + SZ_WP);

    prep_w_only<<<512, 256, 0, stream>>>(wqkv, wproj, wq16, wp16);
    gemm_a32<<<9216, 256, 0, stream>>>(x, wq16, qkv, 2304, 18);
    attn64<<<12288, 256, 0, stream>>>(qkv);
    gemm_bt<true, float><<<3072, 256, 0, stream>>>(qkv, 2304, wp16, bias, out, 768, 6);
  } else if (ws_size >= SZ_WQ + SZ_WP) {
    h16* wq16 = (h16*)d_ws;
    h16* wp16 = (h16*)((char*)d_ws + SZ_WQ);
    prep_w_only<<<512, 256, 0, stream>>>(wqkv, wproj, wq16, wp16);
    fused_fb<h16><<<1024, 512, 0, stream>>>(x, wq16, wp16, bias, out);
  } else {
    fused_fb<float><<<1024, 512, 0, stream>>>(x, wqkv, wproj, bias, out);
  }
}

// Round 7
// 537.664 us; speedup vs baseline: 1.6625x; 1.6625x over previous
//
#include <hip/hip_runtime.h>

// RowAreaAttention split pipeline (round 7):
//  K0 prep_cvt: f32->f16 (w_qkv, w_proj, x)
//  K1 qkv_attn: per (128-row block, head): GEMM {Q|K|V} = xh @ wq_h^T (128x192x768,
//     round-3-proven 2-phase/BK=32/swizzled) then in-WG 2x 64-token attention;
//     writes only O (65536 x 768 f16).
//  K3 gemm_bt: out = O @ wp16^T + bias (65536 x 768 x 768) -> f32

#define SCALE 0.125f

typedef _Float16 h16;
typedef h16   half8 __attribute__((ext_vector_type(8)));
typedef float f32x4 __attribute__((ext_vector_type(4)));

typedef const __attribute__((address_space(1))) unsigned int ga_u32;
typedef __attribute__((address_space(3))) unsigned int ls_u32;

// ---------------------------------------------------------------- K0: prep
__device__ __forceinline__ void cvt8(const float* __restrict__ s,
                                     h16* __restrict__ d, int i) {
  const float4 a = ((const float4*)s)[2 * i];
  const float4 b = ((const float4*)s)[2 * i + 1];
  half8 r;
  r[0] = (h16)a.x; r[1] = (h16)a.y; r[2] = (h16)a.z; r[3] = (h16)a.w;
  r[4] = (h16)b.x; r[5] = (h16)b.y; r[6] = (h16)b.z; r[7] = (h16)b.w;
  ((half8*)d)[i] = r;
}

__global__ void prep_cvt(const float* __restrict__ wq, const float* __restrict__ wp,
                         const float* __restrict__ x,
                         h16* __restrict__ wq16, h16* __restrict__ wp16,
                         h16* __restrict__ xh) {
  const int stride = gridDim.x * blockDim.x;
  const int t0 = blockIdx.x * blockDim.x + threadIdx.x;
  for (int i = t0; i < 221184; i += stride) cvt8(wq, wq16, i);   // 2304*768
  for (int i = t0; i < 73728;  i += stride) cvt8(wp, wp16, i);   // 768*768
  for (int i = t0; i < 6291456; i += stride) cvt8(x, xh, i);     // 65536*768
}

__global__ void prep_w_only(const float* __restrict__ wq, const float* __restrict__ wp,
                            h16* __restrict__ wq16, h16* __restrict__ wp16) {
  const int stride = gridDim.x * blockDim.x;
  const int t0 = blockIdx.x * blockDim.x + threadIdx.x;
  for (int i = t0; i < 221184; i += stride) cvt8(wq, wq16, i);
  for (int i = t0; i < 73728;  i += stride) cvt8(wp, wp16, i);
}

// -------------------------------------- K1: fused QKV-GEMM + attention per head
// Grid: 512 row-tiles x 12 heads. WG = 256 thr (4 waves).
// GEMM: C(128x192) = A(128x768) @ B(192x768)^T, BK=32, 24 steps, 2-phase dbuf,
//   round-3 swizzle (zero conflicts measured). B rows 0-63=Q,64-127=K,128-191=V
//   of head h. Wave (wr,wc): rows wr*64+, cols wc*96+ (6 frags).
// Attn: scatter acc -> sQ/sK/sV(+8 pad), per-wave 32 q-rows: S=QK^T (max-free
//   softmax in regs), P->sQ, O=PV -> sK, vectorized O store (only output).
__global__ __launch_bounds__(256)
void qkv_attn(const h16* __restrict__ A,      // xh (65536 x 768)
              const h16* __restrict__ B,      // wq16 (2304 x 768)
              h16* __restrict__ O) {          // obuf (65536 x 768)
  __shared__ h16 smem[27648];                 // 54 KB union
  h16* As0 = smem;                            // GEMM: [2][4096]
  h16* Bs0 = smem + 8192;                     // GEMM: [2][6144]
  h16* sQ  = smem;                            // attn: [128][72]
  h16* sK  = smem + 9216;                     // attn: [128][72]
  h16* sV  = smem + 18432;                    // attn: [2][64][72] (V^T per group)

  const int nwg = gridDim.x;                  // 6144
  const int bid = blockIdx.x;
  const int wg  = (bid & 7) * (nwg >> 3) + (bid >> 3);   // XCD-chunked swizzle
  const int mt = wg / 12, h = wg - mt * 12;
  const int m0 = mt * 128;

  const int tid  = threadIdx.x;
  const int lane = tid & 63;
  const int wv   = tid >> 6;       // 0..3
  const int l16  = lane & 15;
  const int kg   = lane >> 4;
  const int wr   = wv >> 1;        // row half (also: group index)
  const int wc   = wv & 1;         // col half (96)

  // ---- staging pointers
  const h16* pa[2];
  int loA[2];
  #pragma unroll
  for (int i = 0; i < 2; ++i) {
    const int r  = wv * 32 + i * 16 + (lane >> 2);
    const int cg = (lane & 3) ^ ((r >> 1) & 3);
    pa[i]  = A + (size_t)(m0 + r) * 768 + cg * 8;
    loA[i] = wv * 1024 + i * 512;
  }
  const h16* pb[3];
  int loB[3];
  #pragma unroll
  for (int i = 0; i < 3; ++i) {
    const int r  = wv * 48 + i * 16 + (lane >> 2);       // tile row 0..191
    const int gr = (r >> 6) * 768 + h * 64 + (r & 63);   // global wq row
    const int cg = (lane & 3) ^ ((r >> 1) & 3);
    pb[i]  = B + (size_t)gr * 768 + cg * 8;
    loB[i] = wv * 1536 + i * 512;
  }

#define GLDS(srcp, ldsp)                                                       \
  __builtin_amdgcn_global_load_lds((ga_u32*)(const void*)(srcp),               \
                                   (ls_u32*)(void*)(ldsp), 16, 0, 0)
#define STAGE(bf, koff)                                                        \
  do {                                                                         \
    GLDS(pa[0] + (koff), &As0[(bf) * 4096 + loA[0]]);                          \
    GLDS(pa[1] + (koff), &As0[(bf) * 4096 + loA[1]]);                          \
    GLDS(pb[0] + (koff), &Bs0[(bf) * 6144 + loB[0]]);                          \
    GLDS(pb[1] + (koff), &Bs0[(bf) * 6144 + loB[1]]);                          \
    GLDS(pb[2] + (koff), &Bs0[(bf) * 6144 + loB[2]]);                          \
  } while (0)

  // ---- fragment read offsets (swizzled; frag bases are multiples of 16 rows)
  const int s   = (l16 >> 1) & 3;
  const int ofA = (wr * 64 + l16) * 32 + ((kg ^ s) * 8);       // + mi*512
  const int ofB = (wc * 96 + l16) * 32 + ((kg ^ s) * 8);       // + ni*512

  f32x4 acc[4][6];
  #pragma unroll
  for (int mi = 0; mi < 4; ++mi)
    #pragma unroll
    for (int ni = 0; ni < 6; ++ni)
      acc[mi][ni] = (f32x4){0.f, 0.f, 0.f, 0.f};

  STAGE(0, 0);
  asm volatile("s_waitcnt vmcnt(0)" ::: "memory");
  __syncthreads();

  int cur = 0;
  for (int t = 0; t < 24; ++t) {
    if (t < 23) STAGE(cur ^ 1, (t + 1) * 32);
    half8 af[4], bf8[6];
    #pragma unroll
    for (int mi = 0; mi < 4; ++mi) af[mi]  = *(const half8*)&As0[cur * 4096 + ofA + mi * 512];
    #pragma unroll
    for (int ni = 0; ni < 6; ++ni) bf8[ni] = *(const half8*)&Bs0[cur * 6144 + ofB + ni * 512];
    #pragma unroll
    for (int mi = 0; mi < 4; ++mi)
      #pragma unroll
      for (int ni = 0; ni < 6; ++ni)
        acc[mi][ni] = __builtin_amdgcn_mfma_f32_16x16x32_f16(af[mi], bf8[ni], acc[mi][ni], 0, 0, 0);
    asm volatile("s_waitcnt vmcnt(0)" ::: "memory");
    __syncthreads();
    cur ^= 1;
  }
#undef STAGE
#undef GLDS

  // ---- scatter acc -> sQ / sK / sV (all waves past final LDS reads)
  #pragma unroll
  for (int mi = 0; mi < 4; ++mi) {
    const int rowb = wr * 64 + mi * 16 + kg * 4;     // token row in 128
    const int r6   = (rowb & 63);                    // token within group
    #pragma unroll
    for (int ni = 0; ni < 6; ++ni) {
      const int cbase = wc * 96 + ni * 16;           // wave-uniform
      const int sel = cbase >> 6;
      const int d   = (cbase & 63) + l16;
      if (sel == 0) {
        #pragma unroll
        for (int j = 0; j < 4; ++j) sQ[(rowb + j) * 72 + d] = (h16)acc[mi][ni][j];
      } else if (sel == 1) {
        #pragma unroll
        for (int j = 0; j < 4; ++j) sK[(rowb + j) * 72 + d] = (h16)acc[mi][ni][j];
      } else {
        #pragma unroll
        for (int j = 0; j < 4; ++j) sV[wr * 4608 + d * 72 + r6 + j] = (h16)acc[mi][ni][j];
      }
    }
  }
  __syncthreads();

  // ---- attention: wave handles 32 q-rows of group wr
  const int qr0 = wr * 64 + wc * 32;                 // base q-row (token in 128)

  f32x4 sacc[2][4];
  #pragma unroll
  for (int rb = 0; rb < 2; ++rb)
    #pragma unroll
    for (int cb = 0; cb < 4; ++cb) sacc[rb][cb] = (f32x4){0.f, 0.f, 0.f, 0.f};

  #pragma unroll
  for (int ks = 0; ks < 2; ++ks) {
    half8 aq[2];
    #pragma unroll
    for (int rb = 0; rb < 2; ++rb)
      aq[rb] = *(const half8*)&sQ[(qr0 + rb * 16 + l16) * 72 + ks * 32 + kg * 8];
    #pragma unroll
    for (int cb = 0; cb < 4; ++cb) {
      const half8 kf = *(const half8*)&sK[(wr * 64 + cb * 16 + l16) * 72 + ks * 32 + kg * 8];
      #pragma unroll
      for (int rb = 0; rb < 2; ++rb)
        sacc[rb][cb] = __builtin_amdgcn_mfma_f32_16x16x32_f16(aq[rb], kf, sacc[rb][cb], 0, 0, 0);
    }
  }

  // max-free softmax (|S*scale| << 88): row = qr0 + rb*16 + kg*4 + j
  float e[2][4][4];
  #pragma unroll
  for (int rb = 0; rb < 2; ++rb) {
    float rs[4];
    #pragma unroll
    for (int j = 0; j < 4; ++j) {
      float t = 0.f;
      #pragma unroll
      for (int cb = 0; cb < 4; ++cb) { e[rb][cb][j] = __expf(sacc[rb][cb][j] * SCALE); t += e[rb][cb][j]; }
      rs[j] = t;
    }
    #pragma unroll
    for (int m = 1; m < 16; m <<= 1)
      #pragma unroll
      for (int j = 0; j < 4; ++j) rs[j] += __shfl_xor(rs[j], m);
    #pragma unroll
    for (int j = 0; j < 4; ++j) rs[j] = __fdividef(1.0f, rs[j]);
    #pragma unroll
    for (int cb = 0; cb < 4; ++cb)
      #pragma unroll
      for (int j = 0; j < 4; ++j)
        sQ[(qr0 + rb * 16 + kg * 4 + j) * 72 + cb * 16 + l16] = (h16)(e[rb][cb][j] * rs[j]);
  }
  __syncthreads();

  // ---- O = P V
  f32x4 oacc[2][4];
  #pragma unroll
  for (int rb = 0; rb < 2; ++rb)
    #pragma unroll
    for (int cb = 0; cb < 4; ++cb) oacc[rb][cb] = (f32x4){0.f, 0.f, 0.f, 0.f};
  #pragma unroll
  for (int ks = 0; ks < 2; ++ks) {
    half8 ap[2];
    #pragma unroll
    for (int rb = 0; rb < 2; ++rb)
      ap[rb] = *(const half8*)&sQ[(qr0 + rb * 16 + l16) * 72 + ks * 32 + kg * 8];
    #pragma unroll
    for (int cb = 0; cb < 4; ++cb) {
      const half8 vf = *(const half8*)&sV[wr * 4608 + (cb * 16 + l16) * 72 + ks * 32 + kg * 8];
      #pragma unroll
      for (int rb = 0; rb < 2; ++rb)
        oacc[rb][cb] = __builtin_amdgcn_mfma_f32_16x16x32_f16(ap[rb], vf, oacc[rb][cb], 0, 0, 0);
    }
  }

  // O -> sK (dead), then vectorized store
  #pragma unroll
  for (int rb = 0; rb < 2; ++rb)
    #pragma unroll
    for (int cb = 0; cb < 4; ++cb)
      #pragma unroll
      for (int j = 0; j < 4; ++j)
        sK[(qr0 + rb * 16 + kg * 4 + j) * 72 + cb * 16 + l16] = (h16)oacc[rb][cb][j];
  __syncthreads();
  #pragma unroll
  for (int c = tid; c < 1024; c += 256) {
    const int row = c >> 3, d0 = (c & 7) * 8;
    *(half8*)(O + (size_t)(m0 + row) * 768 + h * 64 + d0) = *(const half8*)&sK[row * 72 + d0];
  }
}

// ------------------------------------------------------- K3: gemm_bt (round-3)
// C(M x N) = A(M x 768 f16, lda) @ B(N x 768 f16)^T [+ bias], 128x128, BK=32.
template <bool BIAS, typename OutT>
__global__ void gemm_bt(const h16* __restrict__ A, int lda,
                        const h16* __restrict__ B,
                        const float* __restrict__ bias,
                        OutT* __restrict__ C, int ldc,
                        int ntiles) {
  __shared__ h16 As[2][4096];
  __shared__ h16 Bs[2][4096];

  const int nwg = gridDim.x;
  const int bid = blockIdx.x;
  const int wg  = (bid & 7) * (nwg >> 3) + (bid >> 3);
  const int mt = wg / ntiles, nt = wg - mt * ntiles;
  const int m0 = mt * 128, n0 = nt * 128;

  const int tid  = threadIdx.x;
  const int lane = tid & 63;
  const int wv   = tid >> 6;
  const int l16  = lane & 15;
  const int kg   = lane >> 4;

  const h16* pa[2];
  const h16* pb[2];
  int lo[2];
  #pragma unroll
  for (int i = 0; i < 2; ++i) {
    const int row = wv * 32 + i * 16 + (lane >> 2);
    const int cg  = (lane & 3) ^ ((row >> 1) & 3);
    pa[i] = A + (size_t)(m0 + row) * lda + cg * 8;
    pb[i] = B + (size_t)(n0 + row) * 768 + cg * 8;
    lo[i] = wv * 1024 + i * 512;
  }

#define STAGE(bf, koff)                                                        \
  do {                                                                         \
    __builtin_amdgcn_global_load_lds((ga_u32*)(const void*)(pa[0] + (koff)),   \
                                     (ls_u32*)(void*)&As[bf][lo[0]], 16, 0, 0);\
    __builtin_amdgcn_global_load_lds((ga_u32*)(const void*)(pb[0] + (koff)),   \
                                     (ls_u32*)(void*)&Bs[bf][lo[0]], 16, 0, 0);\
    __builtin_amdgcn_global_load_lds((ga_u32*)(const void*)(pa[1] + (koff)),   \
                                     (ls_u32*)(void*)&As[bf][lo[1]], 16, 0, 0);\
    __builtin_amdgcn_global_load_lds((ga_u32*)(const void*)(pb[1] + (koff)),   \
                                     (ls_u32*)(void*)&Bs[bf][lo[1]], 16, 0, 0);\
  } while (0)

  const int s   = (l16 >> 1) & 3;
  const int wr  = wv >> 1, wc = wv & 1;
  const int ofA = (wr * 64 + l16) * 32 + ((kg ^ s) * 8);
  const int ofB = (wc * 64 + l16) * 32 + ((kg ^ s) * 8);

  f32x4 acc[4][4];
  #pragma unroll
  for (int mi = 0; mi < 4; ++mi)
    #pragma unroll
    for (int ni = 0; ni < 4; ++ni)
      acc[mi][ni] = (f32x4){0.f, 0.f, 0.f, 0.f};

  STAGE(0, 0);
  asm volatile("s_waitcnt vmcnt(0)" ::: "memory");
  __syncthreads();

  int cur = 0;
  for (int t = 0; t < 24; ++t) {
    if (t < 23) STAGE(cur ^ 1, (t + 1) * 32);
    half8 af[4], bf8[4];
    #pragma unroll
    for (int mi = 0; mi < 4; ++mi) af[mi]  = *(const half8*)&As[cur][ofA + mi * 512];
    #pragma unroll
    for (int ni = 0; ni < 4; ++ni) bf8[ni] = *(const half8*)&Bs[cur][ofB + ni * 512];
    #pragma unroll
    for (int mi = 0; mi < 4; ++mi)
      #pragma unroll
      for (int ni = 0; ni < 4; ++ni)
        acc[mi][ni] = __builtin_amdgcn_mfma_f32_16x16x32_f16(af[mi], bf8[ni], acc[mi][ni], 0, 0, 0);
    asm volatile("s_waitcnt vmcnt(0)" ::: "memory");
    __syncthreads();
    cur ^= 1;
  }
#undef STAGE

  float bv[4];
  if (BIAS) {
    #pragma unroll
    for (int ni = 0; ni < 4; ++ni) bv[ni] = bias[n0 + wc * 64 + ni * 16 + l16];
  }
  #pragma unroll
  for (int mi = 0; mi < 4; ++mi) {
    #pragma unroll
    for (int ni = 0; ni < 4; ++ni) {
      const int col = n0 + wc * 64 + ni * 16 + l16;
      #pragma unroll
      for (int j = 0; j < 4; ++j) {
        const int row = m0 + wr * 64 + mi * 16 + kg * 4 + j;
        if (BIAS) C[(size_t)row * ldc + col] = (OutT)(acc[mi][ni][j] + bv[ni]);
        else      C[(size_t)row * ldc + col] = (OutT)acc[mi][ni][j];
      }
    }
  }
}

// ------------------------------------------- fallback: fused kernel (small ws)
template <typename WT>
__device__ __forceinline__ half8 loadw8(const WT* p);
template <>
__device__ __forceinline__ half8 loadw8<h16>(const h16* p) { return *(const half8*)p; }
template <>
__device__ __forceinline__ half8 loadw8<float>(const float* p) {
  const float4 a = *(const float4*)p;
  const float4 b = *(const float4*)(p + 4);
  half8 r;
  r[0] = (h16)a.x; r[1] = (h16)a.y; r[2] = (h16)a.z; r[3] = (h16)a.w;
  r[4] = (h16)b.x; r[5] = (h16)b.y; r[6] = (h16)b.z; r[7] = (h16)b.w;
  return r;
}

template <typename WT>
__launch_bounds__(512, 2)
__global__ void fused_fb(const float* __restrict__ x,
                         const WT* __restrict__ wq,
                         const WT* __restrict__ wp,
                         const float* __restrict__ bias,
                         float* __restrict__ out) {
  __shared__ h16   xs[64][776];
  __shared__ h16   qs[64][72];
  __shared__ h16   ks[64][72];
  __shared__ h16   vt[64][72];
  __shared__ float sS[64][68];

  const int g = blockIdx.x, tid = threadIdx.x;
  const int wv = tid >> 6, lane = tid & 63, l16 = lane & 15, kg = lane >> 4;

  const float* xg = x + (size_t)g * (64 * 768);
  #pragma unroll
  for (int i = 0; i < 24; ++i) {
    const int idx = tid + i * 512;
    const int row = idx / 192;
    const int c4  = (idx - row * 192) * 4;
    const float4 v = ((const float4*)xg)[idx];
    h16* p = &xs[row][c4];
    p[0] = (h16)v.x; p[1] = (h16)v.y; p[2] = (h16)v.z; p[3] = (h16)v.w;
  }

  f32x4 acc[4][6];
  #pragma unroll
  for (int a = 0; a < 4; ++a)
    #pragma unroll
    for (int b = 0; b < 6; ++b) acc[a][b] = (f32x4){0.f, 0.f, 0.f, 0.f};

  float bcol[6];
  #pragma unroll
  for (int cb = 0; cb < 6; ++cb) bcol[cb] = bias[wv * 96 + cb * 16 + l16];

  const int r0 = (wv & 1) * 32, c0 = (wv >> 1) * 48;
  const int rS = (wv >> 1) * 16, cS = (wv & 1) * 32;
  __syncthreads();

  for (int h = 0; h < 12; ++h) {
    f32x4 facc[2][3];
    #pragma unroll
    for (int a = 0; a < 2; ++a)
      #pragma unroll
      for (int b = 0; b < 3; ++b) facc[a][b] = (f32x4){0.f, 0.f, 0.f, 0.f};
    int wrow[3];
    #pragma unroll
    for (int cb = 0; cb < 3; ++cb) {
      const int n = c0 + cb * 16;
      wrow[cb] = (n >> 6) * 768 + h * 64 + (n & 63) + l16;
    }
    for (int k0 = 0; k0 < 768; k0 += 32) {
      const half8 a0 = *(const half8*)&xs[r0 + l16][k0 + kg * 8];
      const half8 a1 = *(const half8*)&xs[r0 + 16 + l16][k0 + kg * 8];
      #pragma unroll
      for (int cb = 0; cb < 3; ++cb) {
        const half8 b = loadw8<WT>(wq + (size_t)wrow[cb] * 768 + k0 + kg * 8);
        facc[0][cb] = __builtin_amdgcn_mfma_f32_16x16x32_f16(a0, b, facc[0][cb], 0, 0, 0);
        facc[1][cb] = __builtin_amdgcn_mfma_f32_16x16x32_f16(a1, b, facc[1][cb], 0, 0, 0);
      }
    }
    #pragma unroll
    for (int rb = 0; rb < 2; ++rb)
      #pragma unroll
      for (int cb = 0; cb < 3; ++cb) {
        const int col = c0 + cb * 16 + l16;
        const int rowb = r0 + rb * 16 + kg * 4;
        if (col < 64) {
          #pragma unroll
          for (int j = 0; j < 4; ++j) qs[rowb + j][col] = (h16)facc[rb][cb][j];
        } else if (col < 128) {
          #pragma unroll
          for (int j = 0; j < 4; ++j) ks[rowb + j][col - 64] = (h16)facc[rb][cb][j];
        } else {
          #pragma unroll
          for (int j = 0; j < 4; ++j) vt[col - 128][rowb + j] = (h16)facc[rb][cb][j];
        }
      }
    __syncthreads();

    f32x4 sacc[2];
    sacc[0] = (f32x4){0.f, 0.f, 0.f, 0.f};
    sacc[1] = (f32x4){0.f, 0.f, 0.f, 0.f};
    #pragma unroll
    for (int k0 = 0; k0 < 64; k0 += 32) {
      const half8 aq = *(const half8*)&qs[rS + l16][k0 + kg * 8];
      const half8 b0 = *(const half8*)&ks[cS + l16][k0 + kg * 8];
      const half8 b1 = *(const half8*)&ks[cS + 16 + l16][k0 + kg * 8];
      sacc[0] = __builtin_amdgcn_mfma_f32_16x16x32_f16(aq, b0, sacc[0], 0, 0, 0);
      sacc[1] = __builtin_amdgcn_mfma_f32_16x16x32_f16(aq, b1, sacc[1], 0, 0, 0);
    }
    #pragma unroll
    for (int t = 0; t < 2; ++t)
      #pragma unroll
      for (int j = 0; j < 4; ++j)
        sS[rS + kg * 4 + j][cS + t * 16 + l16] = sacc[t][j] * SCALE;
    __syncthreads();

    {
      const int row = tid >> 3, j0 = (tid & 7) * 8;
      float v0[8];
      #pragma unroll
      for (int i = 0; i < 8; ++i) v0[i] = sS[row][j0 + i];
      float m = v0[0];
      #pragma unroll
      for (int i = 1; i < 8; ++i) m = fmaxf(m, v0[i]);
      m = fmaxf(m, __shfl_xor(m, 1));
      m = fmaxf(m, __shfl_xor(m, 2));
      m = fmaxf(m, __shfl_xor(m, 4));
      float e[8], ssum = 0.f;
      #pragma unroll
      for (int i = 0; i < 8; ++i) { e[i] = __expf(v0[i] - m); ssum += e[i]; }
      ssum += __shfl_xor(ssum, 1);
      ssum += __shfl_xor(ssum, 2);
      ssum += __shfl_xor(ssum, 4);
      const float inv = 1.0f / ssum;
      #pragma unroll
      for (int i = 0; i < 8; ++i) qs[row][j0 + i] = (h16)(e[i] * inv);
    }
    __syncthreads();

    f32x4 oacc[2];
    oacc[0] = (f32x4){0.f, 0.f, 0.f, 0.f};
    oacc[1] = (f32x4){0.f, 0.f, 0.f, 0.f};
    #pragma unroll
    for (int k0 = 0; k0 < 64; k0 += 32) {
      const half8 ap = *(const half8*)&qs[rS + l16][k0 + kg * 8];
      const half8 b0 = *(const half8*)&vt[cS + l16][k0 + kg * 8];
      const half8 b1 = *(const half8*)&vt[cS + 16 + l16][k0 + kg * 8];
      oacc[0] = __builtin_amdgcn_mfma_f32_16x16x32_f16(ap, b0, oacc[0], 0, 0, 0);
      oacc[1] = __builtin_amdgcn_mfma_f32_16x16x32_f16(ap, b1, oacc[1], 0, 0, 0);
    }
    #pragma unroll
    for (int t = 0; t < 2; ++t)
      #pragma unroll
      for (int j = 0; j < 4; ++j)
        ks[rS + kg * 4 + j][cS + t * 16 + l16] = (h16)oacc[t][j];
    __syncthreads();

    #pragma unroll
    for (int k0 = 0; k0 < 64; k0 += 32) {
      half8 ah[4];
      #pragma unroll
      for (int rb = 0; rb < 4; ++rb)
        ah[rb] = *(const half8*)&ks[rb * 16 + l16][k0 + kg * 8];
      #pragma unroll
      for (int cb = 0; cb < 6; ++cb) {
        const int ocol = wv * 96 + cb * 16 + l16;
        const half8 bw = loadw8<WT>(wp + (size_t)ocol * 768 + h * 64 + k0 + kg * 8);
        #pragma unroll
        for (int rb = 0; rb < 4; ++rb)
          acc[rb][cb] = __builtin_amdgcn_mfma_f32_16x16x32_f16(ah[rb], bw, acc[rb][cb], 0, 0, 0);
      }
    }
    __syncthreads();
  }

  float* og = out + (size_t)g * (64 * 768);
  #pragma unroll
  for (int rb = 0; rb < 4; ++rb)
    #pragma unroll
    for (int cb = 0; cb < 6; ++cb) {
      const int col = wv * 96 + cb * 16 + l16;
      #pragma unroll
      for (int j = 0; j < 4; ++j) {
        const int row = rb * 16 + kg * 4 + j;
        og[(size_t)row * 768 + col] = acc[rb][cb][j] + bcol[cb];
      }
    }
}

// ---------------------------------------------------------------- launch
extern "C" void kernel_launch(void* const* d_in, const int* in_sizes, int n_in,
                              void* d_out, int out_size, void* d_ws, size_t ws_size,
                              hipStream_t stream) {
  const float* x     = (const float*)d_in[0];
  const float* wqkv  = (const float*)d_in[1];
  const float* wproj = (const float*)d_in[2];
  const float* bias  = (const float*)d_in[3];
  float* out = (float*)d_out;

  const size_t SZ_WQ = (size_t)2304 * 768 * sizeof(h16);   //   3.54 MB
  const size_t SZ_WP = (size_t)768 * 768 * sizeof(h16);    //   1.18 MB
  const size_t SZ_XH = (size_t)65536 * 768 * sizeof(h16);  // 100.66 MB
  const size_t SZ_O  = (size_t)65536 * 768 * sizeof(h16);  // 100.66 MB

  if (ws_size >= SZ_WQ + SZ_WP + SZ_XH + SZ_O) {
    h16* wq16 = (h16*)d_ws;
    h16* wp16 = (h16*)((char*)d_ws + SZ_WQ);
    h16* xh   = (h16*)((char*)d_ws + SZ_WQ + SZ_WP);
    h16* obuf = (h16*)((char*)d_ws + SZ_WQ + SZ_WP + SZ_XH);

    prep_cvt<<<2048, 256, 0, stream>>>(wqkv, wproj, x, wq16, wp16, xh);
    qkv_attn<<<6144, 256, 0, stream>>>(xh, wq16, obuf);
    gemm_bt<true, float><<<3072, 256, 0, stream>>>(obuf, 768, wp16, bias, out, 768, 6);
  } else if (ws_size >= SZ_WQ + SZ_WP) {
    h16* wq16 = (h16*)d_ws;
    h16* wp16 = (h16*)((char*)d_ws + SZ_WQ);
    prep_w_only<<<512, 256, 0, stream>>>(wqkv, wproj, wq16, wp16);
    fused_fb<h16><<<1024, 512, 0, stream>>>(x, wq16, wp16, bias, out);
  } else {
    fused_fb<float><<<1024, 512, 0, stream>>>(x, wqkv, wproj, bias, out);
  }
}

// Round 8
// 476.293 us; speedup vs baseline: 1.8767x; 1.1288x over previous
//
#include <hip/hip_runtime.h>

// RowAreaAttention split pipeline (round 8):
//  K0 prep_cvt: f32->f16 (w_qkv, w_proj, x)
//  K1 qkv_attn: per (128-row block, head): GEMM {Q|K|V} = xh @ wq_h^T (128x192x768)
//     BK=64 2-phase dbuf (12 barriers), round-5-verified zero-conflict swizzle;
//     then in-WG 2x 64-token attention; writes only O (65536 x 768 f16).
//  K3 gemm_bt: out = O @ wp16^T + bias (65536 x 768 x 768) -> f32

#define SCALE 0.125f

typedef _Float16 h16;
typedef h16   half8 __attribute__((ext_vector_type(8)));
typedef float f32x4 __attribute__((ext_vector_type(4)));

typedef const __attribute__((address_space(1))) unsigned int ga_u32;
typedef __attribute__((address_space(3))) unsigned int ls_u32;

// ---------------------------------------------------------------- K0: prep
__device__ __forceinline__ void cvt8(const float* __restrict__ s,
                                     h16* __restrict__ d, int i) {
  const float4 a = ((const float4*)s)[2 * i];
  const float4 b = ((const float4*)s)[2 * i + 1];
  half8 r;
  r[0] = (h16)a.x; r[1] = (h16)a.y; r[2] = (h16)a.z; r[3] = (h16)a.w;
  r[4] = (h16)b.x; r[5] = (h16)b.y; r[6] = (h16)b.z; r[7] = (h16)b.w;
  ((half8*)d)[i] = r;
}

__global__ void prep_cvt(const float* __restrict__ wq, const float* __restrict__ wp,
                         const float* __restrict__ x,
                         h16* __restrict__ wq16, h16* __restrict__ wp16,
                         h16* __restrict__ xh) {
  const int stride = gridDim.x * blockDim.x;
  const int t0 = blockIdx.x * blockDim.x + threadIdx.x;
  for (int i = t0; i < 221184; i += stride) cvt8(wq, wq16, i);   // 2304*768
  for (int i = t0; i < 73728;  i += stride) cvt8(wp, wp16, i);   // 768*768
  for (int i = t0; i < 6291456; i += stride) cvt8(x, xh, i);     // 65536*768
}

__global__ void prep_w_only(const float* __restrict__ wq, const float* __restrict__ wp,
                            h16* __restrict__ wq16, h16* __restrict__ wp16) {
  const int stride = gridDim.x * blockDim.x;
  const int t0 = blockIdx.x * blockDim.x + threadIdx.x;
  for (int i = t0; i < 221184; i += stride) cvt8(wq, wq16, i);
  for (int i = t0; i < 73728;  i += stride) cvt8(wp, wp16, i);
}

// -------------------------------------- K1: fused QKV-GEMM + attention per head
// Grid: 512 row-tiles x 12 heads. WG = 256 thr (4 waves).
// GEMM: C(128x192) = A(128x768) @ B(192x768)^T, BK=64, 12 outer steps,
//   2-phase dbuf; ONE vmcnt(0)+barrier per 64-K (halved vs BK=32).
//   Swizzle (round-5 verified zero-conflict, [rows][64] h16):
//     stage: thread chunk (row, slot=tid&7) reads src col-group (slot ^ (row&7)),
//     read : frag k-chunk (ks*4+kg) at slot ((ks*4+kg) ^ (row&7)), row&7 == l16&7.
// Attn: scatter acc -> sQ/sK/sV(+8 pad), per-wave 32 q-rows: S=QK^T (max-free
//   softmax in regs), P->sQ, O=PV -> sK, vectorized O store (only output).
__global__ __launch_bounds__(256)
void qkv_attn(const h16* __restrict__ A,      // xh (65536 x 768)
              const h16* __restrict__ B,      // wq16 (2304 x 768)
              h16* __restrict__ O) {          // obuf (65536 x 768)
  __shared__ h16 smem[40960];                 // 80 KB union
  h16* As0 = smem;                            // GEMM: [2][8192]  ([128][64] x2)
  h16* Bs0 = smem + 16384;                    // GEMM: [2][12288] ([192][64] x2)
  h16* sQ  = smem;                            // attn: [128][72]
  h16* sK  = smem + 9216;                     // attn: [128][72]
  h16* sV  = smem + 18432;                    // attn: [2][64][72] (V^T per group)

  const int nwg = gridDim.x;                  // 6144
  const int bid = blockIdx.x;
  const int wg  = (bid & 7) * (nwg >> 3) + (bid >> 3);   // XCD-chunked swizzle
  const int mt = wg / 12, h = wg - mt * 12;
  const int m0 = mt * 128;

  const int tid  = threadIdx.x;
  const int lane = tid & 63;
  const int wv   = tid >> 6;       // 0..3
  const int l16  = lane & 15;
  const int kg   = lane >> 4;
  const int wr   = wv >> 1;        // row half (also: group index)
  const int wc   = wv & 1;         // col half (96)

  // ---- staging: thread covers chunk (row = i*32 + tid>>3, slot = tid&7)
  const int srow = tid >> 3;                  // 0..31
  const int cg   = (tid & 7) ^ (srow & 7);    // pre-swizzled src col-group
  const h16* pA[4];
  const h16* pB[6];
  int loA[4], loB[6];
  #pragma unroll
  for (int i = 0; i < 4; ++i) {
    const int r = i * 32 + srow;                         // 0..127
    pA[i]  = A + (size_t)(m0 + r) * 768 + cg * 8;
    loA[i] = (i * 256 + tid) * 8;
  }
  #pragma unroll
  for (int i = 0; i < 6; ++i) {
    const int r  = i * 32 + srow;                        // 0..191
    const int gr = (r >> 6) * 768 + h * 64 + (r & 63);   // global wq row
    pB[i]  = B + (size_t)gr * 768 + cg * 8;
    loB[i] = (i * 256 + tid) * 8;
  }

#define GLDS(srcp, ldsp)                                                       \
  __builtin_amdgcn_global_load_lds((ga_u32*)(const void*)(srcp),               \
                                   (ls_u32*)(void*)(ldsp), 16, 0, 0)
#define STAGE(bf, kt)                                                          \
  do {                                                                         \
    GLDS(pA[0] + (kt) * 64, &As0[(bf) * 8192 + loA[0]]);                       \
    GLDS(pA[1] + (kt) * 64, &As0[(bf) * 8192 + loA[1]]);                       \
    GLDS(pA[2] + (kt) * 64, &As0[(bf) * 8192 + loA[2]]);                       \
    GLDS(pA[3] + (kt) * 64, &As0[(bf) * 8192 + loA[3]]);                       \
    GLDS(pB[0] + (kt) * 64, &Bs0[(bf) * 12288 + loB[0]]);                      \
    GLDS(pB[1] + (kt) * 64, &Bs0[(bf) * 12288 + loB[1]]);                      \
    GLDS(pB[2] + (kt) * 64, &Bs0[(bf) * 12288 + loB[2]]);                      \
    GLDS(pB[3] + (kt) * 64, &Bs0[(bf) * 12288 + loB[3]]);                      \
    GLDS(pB[4] + (kt) * 64, &Bs0[(bf) * 12288 + loB[4]]);                      \
    GLDS(pB[5] + (kt) * 64, &Bs0[(bf) * 12288 + loB[5]]);                      \
  } while (0)

  // ---- fragment read offsets (h16 units, swizzled; frag row&7 == l16&7)
  const int aBase = (wr * 64 + l16) * 64;     // + mi*1024 + axor[ks]
  const int bBase = (wc * 96 + l16) * 64;     // + ni*1024 + axor[ks]
  int axor[2];
  #pragma unroll
  for (int ks = 0; ks < 2; ++ks)
    axor[ks] = ((ks * 4 + kg) ^ (l16 & 7)) * 8;

  f32x4 acc[4][6];
  #pragma unroll
  for (int mi = 0; mi < 4; ++mi)
    #pragma unroll
    for (int ni = 0; ni < 6; ++ni)
      acc[mi][ni] = (f32x4){0.f, 0.f, 0.f, 0.f};

  STAGE(0, 0);
  asm volatile("s_waitcnt vmcnt(0)" ::: "memory");
  __syncthreads();

  int cur = 0;
  for (int t = 0; t < 12; ++t) {
    if (t < 11) STAGE(cur ^ 1, t + 1);
    const h16* Ac = As0 + cur * 8192;
    const h16* Bc = Bs0 + cur * 12288;
    #pragma unroll
    for (int ks = 0; ks < 2; ++ks) {
      half8 af[4], bf8[6];
      #pragma unroll
      for (int mi = 0; mi < 4; ++mi)
        af[mi] = *(const half8*)&Ac[aBase + mi * 1024 + axor[ks]];
      #pragma unroll
      for (int ni = 0; ni < 6; ++ni)
        bf8[ni] = *(const half8*)&Bc[bBase + ni * 1024 + axor[ks]];
      #pragma unroll
      for (int mi = 0; mi < 4; ++mi)
        #pragma unroll
        for (int ni = 0; ni < 6; ++ni)
          acc[mi][ni] = __builtin_amdgcn_mfma_f32_16x16x32_f16(af[mi], bf8[ni], acc[mi][ni], 0, 0, 0);
    }
    asm volatile("s_waitcnt vmcnt(0)" ::: "memory");
    __syncthreads();
    cur ^= 1;
  }
#undef STAGE
#undef GLDS

  // ---- scatter acc -> sQ / sK / sV (all waves past final LDS reads)
  #pragma unroll
  for (int mi = 0; mi < 4; ++mi) {
    const int rowb = wr * 64 + mi * 16 + kg * 4;     // token row in 128
    const int r6   = (rowb & 63);                    // token within group
    #pragma unroll
    for (int ni = 0; ni < 6; ++ni) {
      const int cbase = wc * 96 + ni * 16;           // wave-uniform
      const int sel = cbase >> 6;
      const int d   = (cbase & 63) + l16;
      if (sel == 0) {
        #pragma unroll
        for (int j = 0; j < 4; ++j) sQ[(rowb + j) * 72 + d] = (h16)acc[mi][ni][j];
      } else if (sel == 1) {
        #pragma unroll
        for (int j = 0; j < 4; ++j) sK[(rowb + j) * 72 + d] = (h16)acc[mi][ni][j];
      } else {
        #pragma unroll
        for (int j = 0; j < 4; ++j) sV[wr * 4608 + d * 72 + r6 + j] = (h16)acc[mi][ni][j];
      }
    }
  }
  __syncthreads();

  // ---- attention: wave handles 32 q-rows of group wr
  const int qr0 = wr * 64 + wc * 32;                 // base q-row (token in 128)

  f32x4 sacc[2][4];
  #pragma unroll
  for (int rb = 0; rb < 2; ++rb)
    #pragma unroll
    for (int cb = 0; cb < 4; ++cb) sacc[rb][cb] = (f32x4){0.f, 0.f, 0.f, 0.f};

  #pragma unroll
  for (int ks = 0; ks < 2; ++ks) {
    half8 aq[2];
    #pragma unroll
    for (int rb = 0; rb < 2; ++rb)
      aq[rb] = *(const half8*)&sQ[(qr0 + rb * 16 + l16) * 72 + ks * 32 + kg * 8];
    #pragma unroll
    for (int cb = 0; cb < 4; ++cb) {
      const half8 kf = *(const half8*)&sK[(wr * 64 + cb * 16 + l16) * 72 + ks * 32 + kg * 8];
      #pragma unroll
      for (int rb = 0; rb < 2; ++rb)
        sacc[rb][cb] = __builtin_amdgcn_mfma_f32_16x16x32_f16(aq[rb], kf, sacc[rb][cb], 0, 0, 0);
    }
  }

  // max-free softmax (|S*scale| << 88): row = qr0 + rb*16 + kg*4 + j
  float e[2][4][4];
  #pragma unroll
  for (int rb = 0; rb < 2; ++rb) {
    float rs[4];
    #pragma unroll
    for (int j = 0; j < 4; ++j) {
      float t = 0.f;
      #pragma unroll
      for (int cb = 0; cb < 4; ++cb) { e[rb][cb][j] = __expf(sacc[rb][cb][j] * SCALE); t += e[rb][cb][j]; }
      rs[j] = t;
    }
    #pragma unroll
    for (int m = 1; m < 16; m <<= 1)
      #pragma unroll
      for (int j = 0; j < 4; ++j) rs[j] += __shfl_xor(rs[j], m);
    #pragma unroll
    for (int j = 0; j < 4; ++j) rs[j] = __fdividef(1.0f, rs[j]);
    #pragma unroll
    for (int cb = 0; cb < 4; ++cb)
      #pragma unroll
      for (int j = 0; j < 4; ++j)
        sQ[(qr0 + rb * 16 + kg * 4 + j) * 72 + cb * 16 + l16] = (h16)(e[rb][cb][j] * rs[j]);
  }
  __syncthreads();

  // ---- O = P V
  f32x4 oacc[2][4];
  #pragma unroll
  for (int rb = 0; rb < 2; ++rb)
    #pragma unroll
    for (int cb = 0; cb < 4; ++cb) oacc[rb][cb] = (f32x4){0.f, 0.f, 0.f, 0.f};
  #pragma unroll
  for (int ks = 0; ks < 2; ++ks) {
    half8 ap[2];
    #pragma unroll
    for (int rb = 0; rb < 2; ++rb)
      ap[rb] = *(const half8*)&sQ[(qr0 + rb * 16 + l16) * 72 + ks * 32 + kg * 8];
    #pragma unroll
    for (int cb = 0; cb < 4; ++cb) {
      const half8 vf = *(const half8*)&sV[wr * 4608 + (cb * 16 + l16) * 72 + ks * 32 + kg * 8];
      #pragma unroll
      for (int rb = 0; rb < 2; ++rb)
        oacc[rb][cb] = __builtin_amdgcn_mfma_f32_16x16x32_f16(ap[rb], vf, oacc[rb][cb], 0, 0, 0);
    }
  }

  // O -> sK (dead), then vectorized store
  #pragma unroll
  for (int rb = 0; rb < 2; ++rb)
    #pragma unroll
    for (int cb = 0; cb < 4; ++cb)
      #pragma unroll
      for (int j = 0; j < 4; ++j)
        sK[(qr0 + rb * 16 + kg * 4 + j) * 72 + cb * 16 + l16] = (h16)oacc[rb][cb][j];
  __syncthreads();
  #pragma unroll
  for (int c = tid; c < 1024; c += 256) {
    const int row = c >> 3, d0 = (c & 7) * 8;
    *(half8*)(O + (size_t)(m0 + row) * 768 + h * 64 + d0) = *(const half8*)&sK[row * 72 + d0];
  }
}

// ------------------------------------------------------- K3: gemm_bt (round-3)
// C(M x N) = A(M x 768 f16, lda) @ B(N x 768 f16)^T [+ bias], 128x128, BK=32.
template <bool BIAS, typename OutT>
__global__ void gemm_bt(const h16* __restrict__ A, int lda,
                        const h16* __restrict__ B,
                        const float* __restrict__ bias,
                        OutT* __restrict__ C, int ldc,
                        int ntiles) {
  __shared__ h16 As[2][4096];
  __shared__ h16 Bs[2][4096];

  const int nwg = gridDim.x;
  const int bid = blockIdx.x;
  const int wg  = (bid & 7) * (nwg >> 3) + (bid >> 3);
  const int mt = wg / ntiles, nt = wg - mt * ntiles;
  const int m0 = mt * 128, n0 = nt * 128;

  const int tid  = threadIdx.x;
  const int lane = tid & 63;
  const int wv   = tid >> 6;
  const int l16  = lane & 15;
  const int kg   = lane >> 4;

  const h16* pa[2];
  const h16* pb[2];
  int lo[2];
  #pragma unroll
  for (int i = 0; i < 2; ++i) {
    const int row = wv * 32 + i * 16 + (lane >> 2);
    const int cg  = (lane & 3) ^ ((row >> 1) & 3);
    pa[i] = A + (size_t)(m0 + row) * lda + cg * 8;
    pb[i] = B + (size_t)(n0 + row) * 768 + cg * 8;
    lo[i] = wv * 1024 + i * 512;
  }

#define STAGE(bf, koff)                                                        \
  do {                                                                         \
    __builtin_amdgcn_global_load_lds((ga_u32*)(const void*)(pa[0] + (koff)),   \
                                     (ls_u32*)(void*)&As[bf][lo[0]], 16, 0, 0);\
    __builtin_amdgcn_global_load_lds((ga_u32*)(const void*)(pb[0] + (koff)),   \
                                     (ls_u32*)(void*)&Bs[bf][lo[0]], 16, 0, 0);\
    __builtin_amdgcn_global_load_lds((ga_u32*)(const void*)(pa[1] + (koff)),   \
                                     (ls_u32*)(void*)&As[bf][lo[1]], 16, 0, 0);\
    __builtin_amdgcn_global_load_lds((ga_u32*)(const void*)(pb[1] + (koff)),   \
                                     (ls_u32*)(void*)&Bs[bf][lo[1]], 16, 0, 0);\
  } while (0)

  const int s   = (l16 >> 1) & 3;
  const int wr  = wv >> 1, wc = wv & 1;
  const int ofA = (wr * 64 + l16) * 32 + ((kg ^ s) * 8);
  const int ofB = (wc * 64 + l16) * 32 + ((kg ^ s) * 8);

  f32x4 acc[4][4];
  #pragma unroll
  for (int mi = 0; mi < 4; ++mi)
    #pragma unroll
    for (int ni = 0; ni < 4; ++ni)
      acc[mi][ni] = (f32x4){0.f, 0.f, 0.f, 0.f};

  STAGE(0, 0);
  asm volatile("s_waitcnt vmcnt(0)" ::: "memory");
  __syncthreads();

  int cur = 0;
  for (int t = 0; t < 24; ++t) {
    if (t < 23) STAGE(cur ^ 1, (t + 1) * 32);
    half8 af[4], bf8[4];
    #pragma unroll
    for (int mi = 0; mi < 4; ++mi) af[mi]  = *(const half8*)&As[cur][ofA + mi * 512];
    #pragma unroll
    for (int ni = 0; ni < 4; ++ni) bf8[ni] = *(const half8*)&Bs[cur][ofB + ni * 512];
    #pragma unroll
    for (int mi = 0; mi < 4; ++mi)
      #pragma unroll
      for (int ni = 0; ni < 4; ++ni)
        acc[mi][ni] = __builtin_amdgcn_mfma_f32_16x16x32_f16(af[mi], bf8[ni], acc[mi][ni], 0, 0, 0);
    asm volatile("s_waitcnt vmcnt(0)" ::: "memory");
    __syncthreads();
    cur ^= 1;
  }
#undef STAGE

  float bv[4];
  if (BIAS) {
    #pragma unroll
    for (int ni = 0; ni < 4; ++ni) bv[ni] = bias[n0 + wc * 64 + ni * 16 + l16];
  }
  #pragma unroll
  for (int mi = 0; mi < 4; ++mi) {
    #pragma unroll
    for (int ni = 0; ni < 4; ++ni) {
      const int col = n0 + wc * 64 + ni * 16 + l16;
      #pragma unroll
      for (int j = 0; j < 4; ++j) {
        const int row = m0 + wr * 64 + mi * 16 + kg * 4 + j;
        if (BIAS) C[(size_t)row * ldc + col] = (OutT)(acc[mi][ni][j] + bv[ni]);
        else      C[(size_t)row * ldc + col] = (OutT)acc[mi][ni][j];
      }
    }
  }
}

// ------------------------------------------- fallback: fused kernel (small ws)
template <typename WT>
__device__ __forceinline__ half8 loadw8(const WT* p);
template <>
__device__ __forceinline__ half8 loadw8<h16>(const h16* p) { return *(const half8*)p; }
template <>
__device__ __forceinline__ half8 loadw8<float>(const float* p) {
  const float4 a = *(const float4*)p;
  const float4 b = *(const float4*)(p + 4);
  half8 r;
  r[0] = (h16)a.x; r[1] = (h16)a.y; r[2] = (h16)a.z; r[3] = (h16)a.w;
  r[4] = (h16)b.x; r[5] = (h16)b.y; r[6] = (h16)b.z; r[7] = (h16)b.w;
  return r;
}

template <typename WT>
__launch_bounds__(512, 2)
__global__ void fused_fb(const float* __restrict__ x,
                         const WT* __restrict__ wq,
                         const WT* __restrict__ wp,
                         const float* __restrict__ bias,
                         float* __restrict__ out) {
  __shared__ h16   xs[64][776];
  __shared__ h16   qs[64][72];
  __shared__ h16   ks[64][72];
  __shared__ h16   vt[64][72];
  __shared__ float sS[64][68];

  const int g = blockIdx.x, tid = threadIdx.x;
  const int wv = tid >> 6, lane = tid & 63, l16 = lane & 15, kg = lane >> 4;

  const float* xg = x + (size_t)g * (64 * 768);
  #pragma unroll
  for (int i = 0; i < 24; ++i) {
    const int idx = tid + i * 512;
    const int row = idx / 192;
    const int c4  = (idx - row * 192) * 4;
    const float4 v = ((const float4*)xg)[idx];
    h16* p = &xs[row][c4];
    p[0] = (h16)v.x; p[1] = (h16)v.y; p[2] = (h16)v.z; p[3] = (h16)v.w;
  }

  f32x4 acc[4][6];
  #pragma unroll
  for (int a = 0; a < 4; ++a)
    #pragma unroll
    for (int b = 0; b < 6; ++b) acc[a][b] = (f32x4){0.f, 0.f, 0.f, 0.f};

  float bcol[6];
  #pragma unroll
  for (int cb = 0; cb < 6; ++cb) bcol[cb] = bias[wv * 96 + cb * 16 + l16];

  const int r0 = (wv & 1) * 32, c0 = (wv >> 1) * 48;
  const int rS = (wv >> 1) * 16, cS = (wv & 1) * 32;
  __syncthreads();

  for (int h = 0; h < 12; ++h) {
    f32x4 facc[2][3];
    #pragma unroll
    for (int a = 0; a < 2; ++a)
      #pragma unroll
      for (int b = 0; b < 3; ++b) facc[a][b] = (f32x4){0.f, 0.f, 0.f, 0.f};
    int wrow[3];
    #pragma unroll
    for (int cb = 0; cb < 3; ++cb) {
      const int n = c0 + cb * 16;
      wrow[cb] = (n >> 6) * 768 + h * 64 + (n & 63) + l16;
    }
    for (int k0 = 0; k0 < 768; k0 += 32) {
      const half8 a0 = *(const half8*)&xs[r0 + l16][k0 + kg * 8];
      const half8 a1 = *(const half8*)&xs[r0 + 16 + l16][k0 + kg * 8];
      #pragma unroll
      for (int cb = 0; cb < 3; ++cb) {
        const half8 b = loadw8<WT>(wq + (size_t)wrow[cb] * 768 + k0 + kg * 8);
        facc[0][cb] = __builtin_amdgcn_mfma_f32_16x16x32_f16(a0, b, facc[0][cb], 0, 0, 0);
        facc[1][cb] = __builtin_amdgcn_mfma_f32_16x16x32_f16(a1, b, facc[1][cb], 0, 0, 0);
      }
    }
    #pragma unroll
    for (int rb = 0; rb < 2; ++rb)
      #pragma unroll
      for (int cb = 0; cb < 3; ++cb) {
        const int col = c0 + cb * 16 + l16;
        const int rowb = r0 + rb * 16 + kg * 4;
        if (col < 64) {
          #pragma unroll
          for (int j = 0; j < 4; ++j) qs[rowb + j][col] = (h16)facc[rb][cb][j];
        } else if (col < 128) {
          #pragma unroll
          for (int j = 0; j < 4; ++j) ks[rowb + j][col - 64] = (h16)facc[rb][cb][j];
        } else {
          #pragma unroll
          for (int j = 0; j < 4; ++j) vt[col - 128][rowb + j] = (h16)facc[rb][cb][j];
        }
      }
    __syncthreads();

    f32x4 sacc[2];
    sacc[0] = (f32x4){0.f, 0.f, 0.f, 0.f};
    sacc[1] = (f32x4){0.f, 0.f, 0.f, 0.f};
    #pragma unroll
    for (int k0 = 0; k0 < 64; k0 += 32) {
      const half8 aq = *(const half8*)&qs[rS + l16][k0 + kg * 8];
      const half8 b0 = *(const half8*)&ks[cS + l16][k0 + kg * 8];
      const half8 b1 = *(const half8*)&ks[cS + 16 + l16][k0 + kg * 8];
      sacc[0] = __builtin_amdgcn_mfma_f32_16x16x32_f16(aq, b0, sacc[0], 0, 0, 0);
      sacc[1] = __builtin_amdgcn_mfma_f32_16x16x32_f16(aq, b1, sacc[1], 0, 0, 0);
    }
    #pragma unroll
    for (int t = 0; t < 2; ++t)
      #pragma unroll
      for (int j = 0; j < 4; ++j)
        sS[rS + kg * 4 + j][cS + t * 16 + l16] = sacc[t][j] * SCALE;
    __syncthreads();

    {
      const int row = tid >> 3, j0 = (tid & 7) * 8;
      float v0[8];
      #pragma unroll
      for (int i = 0; i < 8; ++i) v0[i] = sS[row][j0 + i];
      float m = v0[0];
      #pragma unroll
      for (int i = 1; i < 8; ++i) m = fmaxf(m, v0[i]);
      m = fmaxf(m, __shfl_xor(m, 1));
      m = fmaxf(m, __shfl_xor(m, 2));
      m = fmaxf(m, __shfl_xor(m, 4));
      float e[8], ssum = 0.f;
      #pragma unroll
      for (int i = 0; i < 8; ++i) { e[i] = __expf(v0[i] - m); ssum += e[i]; }
      ssum += __shfl_xor(ssum, 1);
      ssum += __shfl_xor(ssum, 2);
      ssum += __shfl_xor(ssum, 4);
      const float inv = 1.0f / ssum;
      #pragma unroll
      for (int i = 0; i < 8; ++i) qs[row][j0 + i] = (h16)(e[i] * inv);
    }
    __syncthreads();

    f32x4 oacc[2];
    oacc[0] = (f32x4){0.f, 0.f, 0.f, 0.f};
    oacc[1] = (f32x4){0.f, 0.f, 0.f, 0.f};
    #pragma unroll
    for (int k0 = 0; k0 < 64; k0 += 32) {
      const half8 ap = *(const half8*)&qs[rS + l16][k0 + kg * 8];
      const half8 b0 = *(const half8*)&vt[cS + l16][k0 + kg * 8];
      const half8 b1 = *(const half8*)&vt[cS + 16 + l16][k0 + kg * 8];
      oacc[0] = __builtin_amdgcn_mfma_f32_16x16x32_f16(ap, b0, oacc[0], 0, 0, 0);
      oacc[1] = __builtin_amdgcn_mfma_f32_16x16x32_f16(ap, b1, oacc[1], 0, 0, 0);
    }
    #pragma unroll
    for (int t = 0; t < 2; ++t)
      #pragma unroll
      for (int j = 0; j < 4; ++j)
        ks[rS + kg * 4 + j][cS + t * 16 + l16] = (h16)oacc[t][j];
    __syncthreads();

    #pragma unroll
    for (int k0 = 0; k0 < 64; k0 += 32) {
      half8 ah[4];
      #pragma unroll
      for (int rb = 0; rb < 4; ++rb)
        ah[rb] = *(const half8*)&ks[rb * 16 + l16][k0 + kg * 8];
      #pragma unroll
      for (int cb = 0; cb < 6; ++cb) {
        const int ocol = wv * 96 + cb * 16 + l16;
        const half8 bw = loadw8<WT>(wp + (size_t)ocol * 768 + h * 64 + k0 + kg * 8);
        #pragma unroll
        for (int rb = 0; rb < 4; ++rb)
          acc[rb][cb] = __builtin_amdgcn_mfma_f32_16x16x32_f16(ah[rb], bw, acc[rb][cb], 0, 0, 0);
      }
    }
    __syncthreads();
  }

  float* og = out + (size_t)g * (64 * 768);
  #pragma unroll
  for (int rb = 0; rb < 4; ++rb)
    #pragma unroll
    for (int cb = 0; cb < 6; ++cb) {
      const int col = wv * 96 + cb * 16 + l16;
      #pragma unroll
      for (int j = 0; j < 4; ++j) {
        const int row = rb * 16 + kg * 4 + j;
        og[(size_t)row * 768 + col] = acc[rb][cb][j] + bcol[cb];
      }
    }
}

// ---------------------------------------------------------------- launch
extern "C" void kernel_launch(void* const* d_in, const int* in_sizes, int n_in,
                              void* d_out, int out_size, void* d_ws, size_t ws_size,
                              hipStream_t stream) {
  const float* x     = (const float*)d_in[0];
  const float* wqkv  = (const float*)d_in[1];
  const float* wproj = (const float*)d_in[2];
  const float* bias  = (const float*)d_in[3];
  float* out = (float*)d_out;

  const size_t SZ_WQ = (size_t)2304 * 768 * sizeof(h16);   //   3.54 MB
  const size_t SZ_WP = (size_t)768 * 768 * sizeof(h16);    //   1.18 MB
  const size_t SZ_XH = (size_t)65536 * 768 * sizeof(h16);  // 100.66 MB
  const size_t SZ_O  = (size_t)65536 * 768 * sizeof(h16);  // 100.66 MB

  if (ws_size >= SZ_WQ + SZ_WP + SZ_XH + SZ_O) {
    h16* wq16 = (h16*)d_ws;
    h16* wp16 = (h16*)((char*)d_ws + SZ_WQ);
    h16* xh   = (h16*)((char*)d_ws + SZ_WQ + SZ_WP);
    h16* obuf = (h16*)((char*)d_ws + SZ_WQ + SZ_WP + SZ_XH);

    prep_cvt<<<2048, 256, 0, stream>>>(wqkv, wproj, x, wq16, wp16, xh);
    qkv_attn<<<6144, 256, 0, stream>>>(xh, wq16, obuf);
    gemm_bt<true, float><<<3072, 256, 0, stream>>>(obuf, 768, wp16, bias, out, 768, 6);
  } else if (ws_size >= SZ_WQ + SZ_WP) {
    h16* wq16 = (h16*)d_ws;
    h16* wp16 = (h16*)((char*)d_ws + SZ_WQ);
    prep_w_only<<<512, 256, 0, stream>>>(wqkv, wproj, wq16, wp16);
    fused_fb<h16><<<1024, 512, 0, stream>>>(x, wq16, wp16, bias, out);
  } else {
    fused_fb<float><<<1024, 512, 0, stream>>>(x, wqkv, wproj, bias, out);
  }
}

// Round 9
// 444.827 us; speedup vs baseline: 2.0094x; 1.0707x over previous
//
#include <hip/hip_runtime.h>

// RowAreaAttention split pipeline (round 9):
//  K0 prep_cvt: f32->f16 (w_qkv, w_proj, x)
//  K1 qkv_attn: per (128-row block, head): GEMM {Q|K|V} = xh @ wq_h^T (128x192x768)
//     BK=64 2-phase dbuf, 8 waves (4Mx2N), zero-conflict swizzle everywhere;
//     then in-WG 2x 64-token attention (XOR-swizzled overlay); writes only O.
//  K3 gemm_bt: out = O @ wp16^T + bias (65536 x 768 x 768) -> f32

#define SCALE 0.125f

typedef _Float16 h16;
typedef h16   half8 __attribute__((ext_vector_type(8)));
typedef float f32x4 __attribute__((ext_vector_type(4)));

typedef const __attribute__((address_space(1))) unsigned int ga_u32;
typedef __attribute__((address_space(3))) unsigned int ls_u32;

// swizzled h16 index into a [R][64] tile: 16B chunk (c>>3) XOR'd with (r&7)
#define SWZ(r, c) (((r) << 6) + ((((c) >> 3) ^ ((r) & 7)) << 3) + ((c) & 7))

// ---------------------------------------------------------------- K0: prep
__device__ __forceinline__ void cvt8(const float* __restrict__ s,
                                     h16* __restrict__ d, int i) {
  const float4 a = ((const float4*)s)[2 * i];
  const float4 b = ((const float4*)s)[2 * i + 1];
  half8 r;
  r[0] = (h16)a.x; r[1] = (h16)a.y; r[2] = (h16)a.z; r[3] = (h16)a.w;
  r[4] = (h16)b.x; r[5] = (h16)b.y; r[6] = (h16)b.z; r[7] = (h16)b.w;
  ((half8*)d)[i] = r;
}

__global__ void prep_cvt(const float* __restrict__ wq, const float* __restrict__ wp,
                         const float* __restrict__ x,
                         h16* __restrict__ wq16, h16* __restrict__ wp16,
                         h16* __restrict__ xh) {
  const int stride = gridDim.x * blockDim.x;
  const int t0 = blockIdx.x * blockDim.x + threadIdx.x;
  for (int i = t0; i < 221184; i += stride) cvt8(wq, wq16, i);   // 2304*768
  for (int i = t0; i < 73728;  i += stride) cvt8(wp, wp16, i);   // 768*768
  for (int i = t0; i < 6291456; i += stride) cvt8(x, xh, i);     // 65536*768
}

__global__ void prep_w_only(const float* __restrict__ wq, const float* __restrict__ wp,
                            h16* __restrict__ wq16, h16* __restrict__ wp16) {
  const int stride = gridDim.x * blockDim.x;
  const int t0 = blockIdx.x * blockDim.x + threadIdx.x;
  for (int i = t0; i < 221184; i += stride) cvt8(wq, wq16, i);
  for (int i = t0; i < 73728;  i += stride) cvt8(wp, wp16, i);
}

// -------------------------------------- K1: fused QKV-GEMM + attention per head
// Grid: 512 row-tiles x 12 heads, WG = 512 thr (8 waves, 4M x 2N).
// GEMM: C(128x192) = A(128x768) @ B(192x768)^T, BK=64, 12 outer steps, 2-phase
//   dbuf, ONE vmcnt(0)+barrier per tile. Swizzle proven zero-conflict (r5/r8).
// Attn overlay (first 48 KB, XOR-swizzled [.][64] tiles, no padding):
//   sQ[128][64] (Q->P), sK[128][64] (K->O), sV[2][64][64] (V^T per group).
// 16 waves/CU (2 WG x 8) = 4 waves/SIMD — double round-8's TLP at same LDS.
__global__ __launch_bounds__(512, 4)
void qkv_attn(const h16* __restrict__ A,      // xh (65536 x 768)
              const h16* __restrict__ B,      // wq16 (2304 x 768)
              h16* __restrict__ O) {          // obuf (65536 x 768)
  __shared__ h16 smem[40960];                 // 80 KB union
  h16* As0 = smem;                            // GEMM: [2][8192]  ([128][64] x2)
  h16* Bs0 = smem + 16384;                    // GEMM: [2][12288] ([192][64] x2)
  h16* sQ  = smem;                            // attn: [128][64] swizzled
  h16* sK  = smem + 8192;                     // attn: [128][64] swizzled
  h16* sV  = smem + 16384;                    // attn: [2][64][64] swizzled (V^T)

  const int nwg = gridDim.x;                  // 6144
  const int bid = blockIdx.x;
  const int wg  = (bid & 7) * (nwg >> 3) + (bid >> 3);   // XCD-chunked swizzle
  const int mt = wg / 12, h = wg - mt * 12;
  const int m0 = mt * 128;

  const int tid  = threadIdx.x;
  const int lane = tid & 63;
  const int wv   = tid >> 6;       // 0..7
  const int l16  = lane & 15;
  const int kg   = lane >> 4;
  const int wr   = wv & 3;         // M quarter (rows wr*32, 2 frags)
  const int wc   = wv >> 2;        // N half   (cols wc*96, 6 frags)

  // ---- staging: thread covers chunk (row = i*64 + tid>>3, slot = tid&7)
  const int srow = tid >> 3;                  // 0..63
  const int slot = tid & 7;
  const int cg   = slot ^ (srow & 7);         // pre-swizzled src col-group
  const h16* pA[2];
  const h16* pB[3];
  int loA[2], loB[3];
  #pragma unroll
  for (int i = 0; i < 2; ++i) {
    const int r = i * 64 + srow;                         // 0..127
    pA[i]  = A + (size_t)(m0 + r) * 768 + cg * 8;
    loA[i] = r * 64 + slot * 8;
  }
  #pragma unroll
  for (int i = 0; i < 3; ++i) {
    const int r  = i * 64 + srow;                        // 0..191
    const int gr = (r >> 6) * 768 + h * 64 + (r & 63);   // global wq row
    pB[i]  = B + (size_t)gr * 768 + cg * 8;
    loB[i] = r * 64 + slot * 8;
  }

#define GLDS(srcp, ldsp)                                                       \
  __builtin_amdgcn_global_load_lds((ga_u32*)(const void*)(srcp),               \
                                   (ls_u32*)(void*)(ldsp), 16, 0, 0)
#define STAGE(bf, kt)                                                          \
  do {                                                                         \
    GLDS(pA[0] + (kt) * 64, &As0[(bf) * 8192 + loA[0]]);                       \
    GLDS(pA[1] + (kt) * 64, &As0[(bf) * 8192 + loA[1]]);                       \
    GLDS(pB[0] + (kt) * 64, &Bs0[(bf) * 12288 + loB[0]]);                      \
    GLDS(pB[1] + (kt) * 64, &Bs0[(bf) * 12288 + loB[1]]);                      \
    GLDS(pB[2] + (kt) * 64, &Bs0[(bf) * 12288 + loB[2]]);                      \
  } while (0)

  // ---- fragment read offsets (h16 units, swizzled; frag row&7 == l16&7)
  const int aBase = (wr * 32 + l16) * 64;     // + mi*1024 + axor[ks]
  const int bBase = (wc * 96 + l16) * 64;     // + ni*1024 + axor[ks]
  int axor[2];
  #pragma unroll
  for (int ks = 0; ks < 2; ++ks)
    axor[ks] = ((ks * 4 + kg) ^ (l16 & 7)) * 8;

  f32x4 acc[2][6];
  #pragma unroll
  for (int mi = 0; mi < 2; ++mi)
    #pragma unroll
    for (int ni = 0; ni < 6; ++ni)
      acc[mi][ni] = (f32x4){0.f, 0.f, 0.f, 0.f};

  STAGE(0, 0);
  asm volatile("s_waitcnt vmcnt(0)" ::: "memory");
  __syncthreads();

  int cur = 0;
  for (int t = 0; t < 12; ++t) {
    if (t < 11) STAGE(cur ^ 1, t + 1);
    const h16* Ac = As0 + cur * 8192;
    const h16* Bc = Bs0 + cur * 12288;
    #pragma unroll
    for (int ks = 0; ks < 2; ++ks) {
      half8 af[2], bf8[6];
      #pragma unroll
      for (int mi = 0; mi < 2; ++mi)
        af[mi] = *(const half8*)&Ac[aBase + mi * 1024 + axor[ks]];
      #pragma unroll
      for (int ni = 0; ni < 6; ++ni)
        bf8[ni] = *(const half8*)&Bc[bBase + ni * 1024 + axor[ks]];
      #pragma unroll
      for (int mi = 0; mi < 2; ++mi)
        #pragma unroll
        for (int ni = 0; ni < 6; ++ni)
          acc[mi][ni] = __builtin_amdgcn_mfma_f32_16x16x32_f16(af[mi], bf8[ni], acc[mi][ni], 0, 0, 0);
    }
    asm volatile("s_waitcnt vmcnt(0)" ::: "memory");
    __syncthreads();
    cur ^= 1;
  }
#undef STAGE
#undef GLDS

  // ---- scatter acc -> sQ / sK / sV (swizzled; all waves past final LDS reads)
  #pragma unroll
  for (int mi = 0; mi < 2; ++mi) {
    const int rowb = wr * 32 + mi * 16 + kg * 4;     // token row in 128
    const int r6   = rowb & 63;                      // token within group
    const int g2s  = rowb >> 6;                      // group of this row
    #pragma unroll
    for (int ni = 0; ni < 6; ++ni) {
      const int cbase = wc * 96 + ni * 16;           // wave-uniform, 0..176
      const int sel = cbase >> 6;
      const int d   = (cbase & 63) + l16;
      if (sel == 0) {
        #pragma unroll
        for (int j = 0; j < 4; ++j) sQ[SWZ(rowb + j, d)] = (h16)acc[mi][ni][j];
      } else if (sel == 1) {
        #pragma unroll
        for (int j = 0; j < 4; ++j) sK[SWZ(rowb + j, d)] = (h16)acc[mi][ni][j];
      } else {
        #pragma unroll
        for (int j = 0; j < 4; ++j) sV[g2s * 4096 + SWZ(d, r6 + j)] = (h16)acc[mi][ni][j];
      }
    }
  }
  __syncthreads();

  // ---- attention: wave handles 16 q-rows [wv*16, wv*16+16), group wv>>2
  const int qr0 = wv * 16;
  const int g2  = wv >> 2;
  const h16* sKg = sK + g2 * 4096;
  const h16* sVg = sV + g2 * 4096;

  f32x4 sacc[4];
  #pragma unroll
  for (int cb = 0; cb < 4; ++cb) sacc[cb] = (f32x4){0.f, 0.f, 0.f, 0.f};
  #pragma unroll
  for (int ks = 0; ks < 2; ++ks) {
    const half8 aq = *(const half8*)&sQ[(qr0 + l16) * 64 + axor[ks]];
    #pragma unroll
    for (int cb = 0; cb < 4; ++cb) {
      const half8 kf = *(const half8*)&sKg[(cb * 16 + l16) * 64 + axor[ks]];
      sacc[cb] = __builtin_amdgcn_mfma_f32_16x16x32_f16(aq, kf, sacc[cb], 0, 0, 0);
    }
  }

  // max-free softmax (|S*scale| << 88): rows qr0 + kg*4 + j
  float e[4][4], rs[4];
  #pragma unroll
  for (int j = 0; j < 4; ++j) {
    float t = 0.f;
    #pragma unroll
    for (int cb = 0; cb < 4; ++cb) { e[cb][j] = __expf(sacc[cb][j] * SCALE); t += e[cb][j]; }
    rs[j] = t;
  }
  #pragma unroll
  for (int m = 1; m < 16; m <<= 1)
    #pragma unroll
    for (int j = 0; j < 4; ++j) rs[j] += __shfl_xor(rs[j], m);
  #pragma unroll
  for (int j = 0; j < 4; ++j) rs[j] = __fdividef(1.0f, rs[j]);

  // P -> sQ (own rows only; no cross-wave readers of these rows)
  #pragma unroll
  for (int cb = 0; cb < 4; ++cb)
    #pragma unroll
    for (int j = 0; j < 4; ++j)
      sQ[SWZ(qr0 + kg * 4 + j, cb * 16 + l16)] = (h16)(e[cb][j] * rs[j]);
  __syncthreads();   // all K-reads done before O overwrites sK

  // ---- O = P V
  f32x4 oacc[4];
  #pragma unroll
  for (int cb = 0; cb < 4; ++cb) oacc[cb] = (f32x4){0.f, 0.f, 0.f, 0.f};
  #pragma unroll
  for (int ks = 0; ks < 2; ++ks) {
    const half8 ap = *(const half8*)&sQ[(qr0 + l16) * 64 + axor[ks]];
    #pragma unroll
    for (int cb = 0; cb < 4; ++cb) {
      const half8 vf = *(const half8*)&sVg[(cb * 16 + l16) * 64 + axor[ks]];
      oacc[cb] = __builtin_amdgcn_mfma_f32_16x16x32_f16(ap, vf, oacc[cb], 0, 0, 0);
    }
  }

  // O -> sK (dead), then chunk-permuted vectorized store (coalesced per segment)
  #pragma unroll
  for (int cb = 0; cb < 4; ++cb)
    #pragma unroll
    for (int j = 0; j < 4; ++j)
      sK[SWZ(qr0 + kg * 4 + j, cb * 16 + l16)] = (h16)oacc[cb][j];
  __syncthreads();
  #pragma unroll
  for (int c = tid; c < 1024; c += 512) {
    const int row = c >> 3, sl = c & 7;
    const int gch = sl ^ (row & 7);            // un-swizzle via permuted dst chunk
    *(half8*)(O + (size_t)(m0 + row) * 768 + h * 64 + gch * 8) =
        *(const half8*)&sK[row * 64 + sl * 8];
  }
}

// ------------------------------------------------------- K3: gemm_bt (round-3)
// C(M x N) = A(M x 768 f16, lda) @ B(N x 768 f16)^T [+ bias], 128x128, BK=32.
template <bool BIAS, typename OutT>
__global__ void gemm_bt(const h16* __restrict__ A, int lda,
                        const h16* __restrict__ B,
                        const float* __restrict__ bias,
                        OutT* __restrict__ C, int ldc,
                        int ntiles) {
  __shared__ h16 As[2][4096];
  __shared__ h16 Bs[2][4096];

  const int nwg = gridDim.x;
  const int bid = blockIdx.x;
  const int wg  = (bid & 7) * (nwg >> 3) + (bid >> 3);
  const int mt = wg / ntiles, nt = wg - mt * ntiles;
  const int m0 = mt * 128, n0 = nt * 128;

  const int tid  = threadIdx.x;
  const int lane = tid & 63;
  const int wv   = tid >> 6;
  const int l16  = lane & 15;
  const int kg   = lane >> 4;

  const h16* pa[2];
  const h16* pb[2];
  int lo[2];
  #pragma unroll
  for (int i = 0; i < 2; ++i) {
    const int row = wv * 32 + i * 16 + (lane >> 2);
    const int cg  = (lane & 3) ^ ((row >> 1) & 3);
    pa[i] = A + (size_t)(m0 + row) * lda + cg * 8;
    pb[i] = B + (size_t)(n0 + row) * 768 + cg * 8;
    lo[i] = wv * 1024 + i * 512;
  }

#define STAGE(bf, koff)                                                        \
  do {                                                                         \
    __builtin_amdgcn_global_load_lds((ga_u32*)(const void*)(pa[0] + (koff)),   \
                                     (ls_u32*)(void*)&As[bf][lo[0]], 16, 0, 0);\
    __builtin_amdgcn_global_load_lds((ga_u32*)(const void*)(pb[0] + (koff)),   \
                                     (ls_u32*)(void*)&Bs[bf][lo[0]], 16, 0, 0);\
    __builtin_amdgcn_global_load_lds((ga_u32*)(const void*)(pa[1] + (koff)),   \
                                     (ls_u32*)(void*)&As[bf][lo[1]], 16, 0, 0);\
    __builtin_amdgcn_global_load_lds((ga_u32*)(const void*)(pb[1] + (koff)),   \
                                     (ls_u32*)(void*)&Bs[bf][lo[1]], 16, 0, 0);\
  } while (0)

  const int s   = (l16 >> 1) & 3;
  const int wr  = wv >> 1, wc = wv & 1;
  const int ofA = (wr * 64 + l16) * 32 + ((kg ^ s) * 8);
  const int ofB = (wc * 64 + l16) * 32 + ((kg ^ s) * 8);

  f32x4 acc[4][4];
  #pragma unroll
  for (int mi = 0; mi < 4; ++mi)
    #pragma unroll
    for (int ni = 0; ni < 4; ++ni)
      acc[mi][ni] = (f32x4){0.f, 0.f, 0.f, 0.f};

  STAGE(0, 0);
  asm volatile("s_waitcnt vmcnt(0)" ::: "memory");
  __syncthreads();

  int cur = 0;
  for (int t = 0; t < 24; ++t) {
    if (t < 23) STAGE(cur ^ 1, (t + 1) * 32);
    half8 af[4], bf8[4];
    #pragma unroll
    for (int mi = 0; mi < 4; ++mi) af[mi]  = *(const half8*)&As[cur][ofA + mi * 512];
    #pragma unroll
    for (int ni = 0; ni < 4; ++ni) bf8[ni] = *(const half8*)&Bs[cur][ofB + ni * 512];
    #pragma unroll
    for (int mi = 0; mi < 4; ++mi)
      #pragma unroll
      for (int ni = 0; ni < 4; ++ni)
        acc[mi][ni] = __builtin_amdgcn_mfma_f32_16x16x32_f16(af[mi], bf8[ni], acc[mi][ni], 0, 0, 0);
    asm volatile("s_waitcnt vmcnt(0)" ::: "memory");
    __syncthreads();
    cur ^= 1;
  }
#undef STAGE

  float bv[4];
  if (BIAS) {
    #pragma unroll
    for (int ni = 0; ni < 4; ++ni) bv[ni] = bias[n0 + wc * 64 + ni * 16 + l16];
  }
  #pragma unroll
  for (int mi = 0; mi < 4; ++mi) {
    #pragma unroll
    for (int ni = 0; ni < 4; ++ni) {
      const int col = n0 + wc * 64 + ni * 16 + l16;
      #pragma unroll
      for (int j = 0; j < 4; ++j) {
        const int row = m0 + wr * 64 + mi * 16 + kg * 4 + j;
        if (BIAS) C[(size_t)row * ldc + col] = (OutT)(acc[mi][ni][j] + bv[ni]);
        else      C[(size_t)row * ldc + col] = (OutT)acc[mi][ni][j];
      }
    }
  }
}

// ------------------------------------------- fallback: fused kernel (small ws)
template <typename WT>
__device__ __forceinline__ half8 loadw8(const WT* p);
template <>
__device__ __forceinline__ half8 loadw8<h16>(const h16* p) { return *(const half8*)p; }
template <>
__device__ __forceinline__ half8 loadw8<float>(const float* p) {
  const float4 a = *(const float4*)p;
  const float4 b = *(const float4*)(p + 4);
  half8 r;
  r[0] = (h16)a.x; r[1] = (h16)a.y; r[2] = (h16)a.z; r[3] = (h16)a.w;
  r[4] = (h16)b.x; r[5] = (h16)b.y; r[6] = (h16)b.z; r[7] = (h16)b.w;
  return r;
}

template <typename WT>
__launch_bounds__(512, 2)
__global__ void fused_fb(const float* __restrict__ x,
                         const WT* __restrict__ wq,
                         const WT* __restrict__ wp,
                         const float* __restrict__ bias,
                         float* __restrict__ out) {
  __shared__ h16   xs[64][776];
  __shared__ h16   qs[64][72];
  __shared__ h16   ks[64][72];
  __shared__ h16   vt[64][72];
  __shared__ float sS[64][68];

  const int g = blockIdx.x, tid = threadIdx.x;
  const int wv = tid >> 6, lane = tid & 63, l16 = lane & 15, kg = lane >> 4;

  const float* xg = x + (size_t)g * (64 * 768);
  #pragma unroll
  for (int i = 0; i < 24; ++i) {
    const int idx = tid + i * 512;
    const int row = idx / 192;
    const int c4  = (idx - row * 192) * 4;
    const float4 v = ((const float4*)xg)[idx];
    h16* p = &xs[row][c4];
    p[0] = (h16)v.x; p[1] = (h16)v.y; p[2] = (h16)v.z; p[3] = (h16)v.w;
  }

  f32x4 acc[4][6];
  #pragma unroll
  for (int a = 0; a < 4; ++a)
    #pragma unroll
    for (int b = 0; b < 6; ++b) acc[a][b] = (f32x4){0.f, 0.f, 0.f, 0.f};

  float bcol[6];
  #pragma unroll
  for (int cb = 0; cb < 6; ++cb) bcol[cb] = bias[wv * 96 + cb * 16 + l16];

  const int r0 = (wv & 1) * 32, c0 = (wv >> 1) * 48;
  const int rS = (wv >> 1) * 16, cS = (wv & 1) * 32;
  __syncthreads();

  for (int h = 0; h < 12; ++h) {
    f32x4 facc[2][3];
    #pragma unroll
    for (int a = 0; a < 2; ++a)
      #pragma unroll
      for (int b = 0; b < 3; ++b) facc[a][b] = (f32x4){0.f, 0.f, 0.f, 0.f};
    int wrow[3];
    #pragma unroll
    for (int cb = 0; cb < 3; ++cb) {
      const int n = c0 + cb * 16;
      wrow[cb] = (n >> 6) * 768 + h * 64 + (n & 63) + l16;
    }
    for (int k0 = 0; k0 < 768; k0 += 32) {
      const half8 a0 = *(const half8*)&xs[r0 + l16][k0 + kg * 8];
      const half8 a1 = *(const half8*)&xs[r0 + 16 + l16][k0 + kg * 8];
      #pragma unroll
      for (int cb = 0; cb < 3; ++cb) {
        const half8 b = loadw8<WT>(wq + (size_t)wrow[cb] * 768 + k0 + kg * 8);
        facc[0][cb] = __builtin_amdgcn_mfma_f32_16x16x32_f16(a0, b, facc[0][cb], 0, 0, 0);
        facc[1][cb] = __builtin_amdgcn_mfma_f32_16x16x32_f16(a1, b, facc[1][cb], 0, 0, 0);
      }
    }
    #pragma unroll
    for (int rb = 0; rb < 2; ++rb)
      #pragma unroll
      for (int cb = 0; cb < 3; ++cb) {
        const int col = c0 + cb * 16 + l16;
        const int rowb = r0 + rb * 16 + kg * 4;
        if (col < 64) {
          #pragma unroll
          for (int j = 0; j < 4; ++j) qs[rowb + j][col] = (h16)facc[rb][cb][j];
        } else if (col < 128) {
          #pragma unroll
          for (int j = 0; j < 4; ++j) ks[rowb + j][col - 64] = (h16)facc[rb][cb][j];
        } else {
          #pragma unroll
          for (int j = 0; j < 4; ++j) vt[col - 128][rowb + j] = (h16)facc[rb][cb][j];
        }
      }
    __syncthreads();

    f32x4 sacc[2];
    sacc[0] = (f32x4){0.f, 0.f, 0.f, 0.f};
    sacc[1] = (f32x4){0.f, 0.f, 0.f, 0.f};
    #pragma unroll
    for (int k0 = 0; k0 < 64; k0 += 32) {
      const half8 aq = *(const half8*)&qs[rS + l16][k0 + kg * 8];
      const half8 b0 = *(const half8*)&ks[cS + l16][k0 + kg * 8];
      const half8 b1 = *(const half8*)&ks[cS + 16 + l16][k0 + kg * 8];
      sacc[0] = __builtin_amdgcn_mfma_f32_16x16x32_f16(aq, b0, sacc[0], 0, 0, 0);
      sacc[1] = __builtin_amdgcn_mfma_f32_16x16x32_f16(aq, b1, sacc[1], 0, 0, 0);
    }
    #pragma unroll
    for (int t = 0; t < 2; ++t)
      #pragma unroll
      for (int j = 0; j < 4; ++j)
        sS[rS + kg * 4 + j][cS + t * 16 + l16] = sacc[t][j] * SCALE;
    __syncthreads();

    {
      const int row = tid >> 3, j0 = (tid & 7) * 8;
      float v0[8];
      #pragma unroll
      for (int i = 0; i < 8; ++i) v0[i] = sS[row][j0 + i];
      float m = v0[0];
      #pragma unroll
      for (int i = 1; i < 8; ++i) m = fmaxf(m, v0[i]);
      m = fmaxf(m, __shfl_xor(m, 1));
      m = fmaxf(m, __shfl_xor(m, 2));
      m = fmaxf(m, __shfl_xor(m, 4));
      float e[8], ssum = 0.f;
      #pragma unroll
      for (int i = 0; i < 8; ++i) { e[i] = __expf(v0[i] - m); ssum += e[i]; }
      ssum += __shfl_xor(ssum, 1);
      ssum += __shfl_xor(ssum, 2);
      ssum += __shfl_xor(ssum, 4);
      const float inv = 1.0f / ssum;
      #pragma unroll
      for (int i = 0; i < 8; ++i) qs[row][j0 + i] = (h16)(e[i] * inv);
    }
    __syncthreads();

    f32x4 oacc[2];
    oacc[0] = (f32x4){0.f, 0.f, 0.f, 0.f};
    oacc[1] = (f32x4){0.f, 0.f, 0.f, 0.f};
    #pragma unroll
    for (int k0 = 0; k0 < 64; k0 += 32) {
      const half8 ap = *(const half8*)&qs[rS + l16][k0 + kg * 8];
      const half8 b0 = *(const half8*)&vt[cS + l16][k0 + kg * 8];
      const half8 b1 = *(const half8*)&vt[cS + 16 + l16][k0 + kg * 8];
      oacc[0] = __builtin_amdgcn_mfma_f32_16x16x32_f16(ap, b0, oacc[0], 0, 0, 0);
      oacc[1] = __builtin_amdgcn_mfma_f32_16x16x32_f16(ap, b1, oacc[1], 0, 0, 0);
    }
    #pragma unroll
    for (int t = 0; t < 2; ++t)
      #pragma unroll
      for (int j = 0; j < 4; ++j)
        ks[rS + kg * 4 + j][cS + t * 16 + l16] = (h16)oacc[t][j];
    __syncthreads();

    #pragma unroll
    for (int k0 = 0; k0 < 64; k0 += 32) {
      half8 ah[4];
      #pragma unroll
      for (int rb = 0; rb < 4; ++rb)
        ah[rb] = *(const half8*)&ks[rb * 16 + l16][k0 + kg * 8];
      #pragma unroll
      for (int cb = 0; cb < 6; ++cb) {
        const int ocol = wv * 96 + cb * 16 + l16;
        const half8 bw = loadw8<WT>(wp + (size_t)ocol * 768 + h * 64 + k0 + kg * 8);
        #pragma unroll
        for (int rb = 0; rb < 4; ++rb)
          acc[rb][cb] = __builtin_amdgcn_mfma_f32_16x16x32_f16(ah[rb], bw, acc[rb][cb], 0, 0, 0);
      }
    }
    __syncthreads();
  }

  float* og = out + (size_t)g * (64 * 768);
  #pragma unroll
  for (int rb = 0; rb < 4; ++rb)
    #pragma unroll
    for (int cb = 0; cb < 6; ++cb) {
      const int col = wv * 96 + cb * 16 + l16;
      #pragma unroll
      for (int j = 0; j < 4; ++j) {
        const int row = rb * 16 + kg * 4 + j;
        og[(size_t)row * 768 + col] = acc[rb][cb][j] + bcol[cb];
      }
    }
}

// ---------------------------------------------------------------- launch
extern "C" void kernel_launch(void* const* d_in, const int* in_sizes, int n_in,
                              void* d_out, int out_size, void* d_ws, size_t ws_size,
                              hipStream_t stream) {
  const float* x     = (const float*)d_in[0];
  const float* wqkv  = (const float*)d_in[1];
  const float* wproj = (const float*)d_in[2];
  const float* bias  = (const float*)d_in[3];
  float* out = (float*)d_out;

  const size_t SZ_WQ = (size_t)2304 * 768 * sizeof(h16);   //   3.54 MB
  const size_t SZ_WP = (size_t)768 * 768 * sizeof(h16);    //   1.18 MB
  const size_t SZ_XH = (size_t)65536 * 768 * sizeof(h16);  // 100.66 MB
  const size_t SZ_O  = (size_t)65536 * 768 * sizeof(h16);  // 100.66 MB

  if (ws_size >= SZ_WQ + SZ_WP + SZ_XH + SZ_O) {
    h16* wq16 = (h16*)d_ws;
    h16* wp16 = (h16*)((char*)d_ws + SZ_WQ);
    h16* xh   = (h16*)((char*)d_ws + SZ_WQ + SZ_WP);
    h16* obuf = (h16*)((char*)d_ws + SZ_WQ + SZ_WP + SZ_XH);

    prep_cvt<<<2048, 256, 0, stream>>>(wqkv, wproj, x, wq16, wp16, xh);
    qkv_attn<<<6144, 512, 0, stream>>>(xh, wq16, obuf);
    gemm_bt<true, float><<<3072, 256, 0, stream>>>(obuf, 768, wp16, bias, out, 768, 6);
  } else if (ws_size >= SZ_WQ + SZ_WP) {
    h16* wq16 = (h16*)d_ws;
    h16* wp16 = (h16*)((char*)d_ws + SZ_WQ);
    prep_w_only<<<512, 256, 0, stream>>>(wqkv, wproj, wq16, wp16);
    fused_fb<h16><<<1024, 512, 0, stream>>>(x, wq16, wp16, bias, out);
  } else {
    fused_fb<float><<<1024, 512, 0, stream>>>(x, wqkv, wproj, bias, out);
  }
}

// Round 10
// 441.713 us; speedup vs baseline: 2.0236x; 1.0070x over previous
//
#include <hip/hip_runtime.h>

// RowAreaAttention split pipeline (round 10):
//  K0 prep_cvt: f32->f16 (w_qkv, w_proj, x)
//  K1 qkv_attn: per (128-row block, head): GEMM {Q|K|V} = xh @ wq_h^T (128x192x768)
//     BK=64 2-phase dbuf, 8 waves (4Mx2N), zero-conflict swizzle; in-WG attention.
//  K3 gemm_bt64: out = O @ wp16^T + bias (65536 x 768 x 768) -> f32
//     SAME 8-wave/BK=64 structure as K1's GEMM (round-9 proven ~950 TF).

#define SCALE 0.125f

typedef _Float16 h16;
typedef h16   half8 __attribute__((ext_vector_type(8)));
typedef float f32x4 __attribute__((ext_vector_type(4)));

typedef const __attribute__((address_space(1))) unsigned int ga_u32;
typedef __attribute__((address_space(3))) unsigned int ls_u32;

// swizzled h16 index into a [R][64] tile: 16B chunk (c>>3) XOR'd with (r&7)
#define SWZ(r, c) (((r) << 6) + ((((c) >> 3) ^ ((r) & 7)) << 3) + ((c) & 7))

// ---------------------------------------------------------------- K0: prep
__device__ __forceinline__ void cvt8(const float* __restrict__ s,
                                     h16* __restrict__ d, int i) {
  const float4 a = ((const float4*)s)[2 * i];
  const float4 b = ((const float4*)s)[2 * i + 1];
  half8 r;
  r[0] = (h16)a.x; r[1] = (h16)a.y; r[2] = (h16)a.z; r[3] = (h16)a.w;
  r[4] = (h16)b.x; r[5] = (h16)b.y; r[6] = (h16)b.z; r[7] = (h16)b.w;
  ((half8*)d)[i] = r;
}

__global__ void prep_cvt(const float* __restrict__ wq, const float* __restrict__ wp,
                         const float* __restrict__ x,
                         h16* __restrict__ wq16, h16* __restrict__ wp16,
                         h16* __restrict__ xh) {
  const int stride = gridDim.x * blockDim.x;
  const int t0 = blockIdx.x * blockDim.x + threadIdx.x;
  for (int i = t0; i < 221184; i += stride) cvt8(wq, wq16, i);   // 2304*768
  for (int i = t0; i < 73728;  i += stride) cvt8(wp, wp16, i);   // 768*768
  for (int i = t0; i < 6291456; i += stride) cvt8(x, xh, i);     // 65536*768
}

__global__ void prep_w_only(const float* __restrict__ wq, const float* __restrict__ wp,
                            h16* __restrict__ wq16, h16* __restrict__ wp16) {
  const int stride = gridDim.x * blockDim.x;
  const int t0 = blockIdx.x * blockDim.x + threadIdx.x;
  for (int i = t0; i < 221184; i += stride) cvt8(wq, wq16, i);
  for (int i = t0; i < 73728;  i += stride) cvt8(wp, wp16, i);
}

// -------------------------------------- K1: fused QKV-GEMM + attention per head
// (unchanged from round 9: 275 us, MfmaUtil 43%, 0.8M conflicts, VGPR 60)
__global__ __launch_bounds__(512, 4)
void qkv_attn(const h16* __restrict__ A,      // xh (65536 x 768)
              const h16* __restrict__ B,      // wq16 (2304 x 768)
              h16* __restrict__ O) {          // obuf (65536 x 768)
  __shared__ h16 smem[40960];                 // 80 KB union
  h16* As0 = smem;                            // GEMM: [2][8192]  ([128][64] x2)
  h16* Bs0 = smem + 16384;                    // GEMM: [2][12288] ([192][64] x2)
  h16* sQ  = smem;                            // attn: [128][64] swizzled
  h16* sK  = smem + 8192;                     // attn: [128][64] swizzled
  h16* sV  = smem + 16384;                    // attn: [2][64][64] swizzled (V^T)

  const int nwg = gridDim.x;                  // 6144
  const int bid = blockIdx.x;
  const int wg  = (bid & 7) * (nwg >> 3) + (bid >> 3);   // XCD-chunked swizzle
  const int mt = wg / 12, h = wg - mt * 12;
  const int m0 = mt * 128;

  const int tid  = threadIdx.x;
  const int lane = tid & 63;
  const int wv   = tid >> 6;       // 0..7
  const int l16  = lane & 15;
  const int kg   = lane >> 4;
  const int wr   = wv & 3;         // M quarter (rows wr*32, 2 frags)
  const int wc   = wv >> 2;        // N half   (cols wc*96, 6 frags)

  // ---- staging: thread covers chunk (row = i*64 + tid>>3, slot = tid&7)
  const int srow = tid >> 3;                  // 0..63
  const int slot = tid & 7;
  const int cg   = slot ^ (srow & 7);         // pre-swizzled src col-group
  const h16* pA[2];
  const h16* pB[3];
  int loA[2], loB[3];
  #pragma unroll
  for (int i = 0; i < 2; ++i) {
    const int r = i * 64 + srow;                         // 0..127
    pA[i]  = A + (size_t)(m0 + r) * 768 + cg * 8;
    loA[i] = r * 64 + slot * 8;
  }
  #pragma unroll
  for (int i = 0; i < 3; ++i) {
    const int r  = i * 64 + srow;                        // 0..191
    const int gr = (r >> 6) * 768 + h * 64 + (r & 63);   // global wq row
    pB[i]  = B + (size_t)gr * 768 + cg * 8;
    loB[i] = r * 64 + slot * 8;
  }

#define GLDS(srcp, ldsp)                                                       \
  __builtin_amdgcn_global_load_lds((ga_u32*)(const void*)(srcp),               \
                                   (ls_u32*)(void*)(ldsp), 16, 0, 0)
#define STAGE(bf, kt)                                                          \
  do {                                                                         \
    GLDS(pA[0] + (kt) * 64, &As0[(bf) * 8192 + loA[0]]);                       \
    GLDS(pA[1] + (kt) * 64, &As0[(bf) * 8192 + loA[1]]);                       \
    GLDS(pB[0] + (kt) * 64, &Bs0[(bf) * 12288 + loB[0]]);                      \
    GLDS(pB[1] + (kt) * 64, &Bs0[(bf) * 12288 + loB[1]]);                      \
    GLDS(pB[2] + (kt) * 64, &Bs0[(bf) * 12288 + loB[2]]);                      \
  } while (0)

  // ---- fragment read offsets (h16 units, swizzled; frag row&7 == l16&7)
  const int aBase = (wr * 32 + l16) * 64;     // + mi*1024 + axor[ks]
  const int bBase = (wc * 96 + l16) * 64;     // + ni*1024 + axor[ks]
  int axor[2];
  #pragma unroll
  for (int ks = 0; ks < 2; ++ks)
    axor[ks] = ((ks * 4 + kg) ^ (l16 & 7)) * 8;

  f32x4 acc[2][6];
  #pragma unroll
  for (int mi = 0; mi < 2; ++mi)
    #pragma unroll
    for (int ni = 0; ni < 6; ++ni)
      acc[mi][ni] = (f32x4){0.f, 0.f, 0.f, 0.f};

  STAGE(0, 0);
  asm volatile("s_waitcnt vmcnt(0)" ::: "memory");
  __syncthreads();

  int cur = 0;
  for (int t = 0; t < 12; ++t) {
    if (t < 11) STAGE(cur ^ 1, t + 1);
    const h16* Ac = As0 + cur * 8192;
    const h16* Bc = Bs0 + cur * 12288;
    #pragma unroll
    for (int ks = 0; ks < 2; ++ks) {
      half8 af[2], bf8[6];
      #pragma unroll
      for (int mi = 0; mi < 2; ++mi)
        af[mi] = *(const half8*)&Ac[aBase + mi * 1024 + axor[ks]];
      #pragma unroll
      for (int ni = 0; ni < 6; ++ni)
        bf8[ni] = *(const half8*)&Bc[bBase + ni * 1024 + axor[ks]];
      #pragma unroll
      for (int mi = 0; mi < 2; ++mi)
        #pragma unroll
        for (int ni = 0; ni < 6; ++ni)
          acc[mi][ni] = __builtin_amdgcn_mfma_f32_16x16x32_f16(af[mi], bf8[ni], acc[mi][ni], 0, 0, 0);
    }
    asm volatile("s_waitcnt vmcnt(0)" ::: "memory");
    __syncthreads();
    cur ^= 1;
  }
#undef STAGE
#undef GLDS

  // ---- scatter acc -> sQ / sK / sV (swizzled; all waves past final LDS reads)
  #pragma unroll
  for (int mi = 0; mi < 2; ++mi) {
    const int rowb = wr * 32 + mi * 16 + kg * 4;     // token row in 128
    const int r6   = rowb & 63;                      // token within group
    const int g2s  = rowb >> 6;                      // group of this row
    #pragma unroll
    for (int ni = 0; ni < 6; ++ni) {
      const int cbase = wc * 96 + ni * 16;           // wave-uniform, 0..176
      const int sel = cbase >> 6;
      const int d   = (cbase & 63) + l16;
      if (sel == 0) {
        #pragma unroll
        for (int j = 0; j < 4; ++j) sQ[SWZ(rowb + j, d)] = (h16)acc[mi][ni][j];
      } else if (sel == 1) {
        #pragma unroll
        for (int j = 0; j < 4; ++j) sK[SWZ(rowb + j, d)] = (h16)acc[mi][ni][j];
      } else {
        #pragma unroll
        for (int j = 0; j < 4; ++j) sV[g2s * 4096 + SWZ(d, r6 + j)] = (h16)acc[mi][ni][j];
      }
    }
  }
  __syncthreads();

  // ---- attention: wave handles 16 q-rows [wv*16, wv*16+16), group wv>>2
  const int qr0 = wv * 16;
  const int g2  = wv >> 2;
  const h16* sKg = sK + g2 * 4096;
  const h16* sVg = sV + g2 * 4096;

  f32x4 sacc[4];
  #pragma unroll
  for (int cb = 0; cb < 4; ++cb) sacc[cb] = (f32x4){0.f, 0.f, 0.f, 0.f};
  #pragma unroll
  for (int ks = 0; ks < 2; ++ks) {
    const half8 aq = *(const half8*)&sQ[(qr0 + l16) * 64 + axor[ks]];
    #pragma unroll
    for (int cb = 0; cb < 4; ++cb) {
      const half8 kf = *(const half8*)&sKg[(cb * 16 + l16) * 64 + axor[ks]];
      sacc[cb] = __builtin_amdgcn_mfma_f32_16x16x32_f16(aq, kf, sacc[cb], 0, 0, 0);
    }
  }

  // max-free softmax (|S*scale| << 88): rows qr0 + kg*4 + j
  float e[4][4], rs[4];
  #pragma unroll
  for (int j = 0; j < 4; ++j) {
    float t = 0.f;
    #pragma unroll
    for (int cb = 0; cb < 4; ++cb) { e[cb][j] = __expf(sacc[cb][j] * SCALE); t += e[cb][j]; }
    rs[j] = t;
  }
  #pragma unroll
  for (int m = 1; m < 16; m <<= 1)
    #pragma unroll
    for (int j = 0; j < 4; ++j) rs[j] += __shfl_xor(rs[j], m);
  #pragma unroll
  for (int j = 0; j < 4; ++j) rs[j] = __fdividef(1.0f, rs[j]);

  // P -> sQ (own rows only; no cross-wave readers of these rows)
  #pragma unroll
  for (int cb = 0; cb < 4; ++cb)
    #pragma unroll
    for (int j = 0; j < 4; ++j)
      sQ[SWZ(qr0 + kg * 4 + j, cb * 16 + l16)] = (h16)(e[cb][j] * rs[j]);
  __syncthreads();   // all K-reads done before O overwrites sK

  // ---- O = P V
  f32x4 oacc[4];
  #pragma unroll
  for (int cb = 0; cb < 4; ++cb) oacc[cb] = (f32x4){0.f, 0.f, 0.f, 0.f};
  #pragma unroll
  for (int ks = 0; ks < 2; ++ks) {
    const half8 ap = *(const half8*)&sQ[(qr0 + l16) * 64 + axor[ks]];
    #pragma unroll
    for (int cb = 0; cb < 4; ++cb) {
      const half8 vf = *(const half8*)&sVg[(cb * 16 + l16) * 64 + axor[ks]];
      oacc[cb] = __builtin_amdgcn_mfma_f32_16x16x32_f16(ap, vf, oacc[cb], 0, 0, 0);
    }
  }

  // O -> sK (dead), then chunk-permuted vectorized store (coalesced per segment)
  #pragma unroll
  for (int cb = 0; cb < 4; ++cb)
    #pragma unroll
    for (int j = 0; j < 4; ++j)
      sK[SWZ(qr0 + kg * 4 + j, cb * 16 + l16)] = (h16)oacc[cb][j];
  __syncthreads();
  #pragma unroll
  for (int c = tid; c < 1024; c += 512) {
    const int row = c >> 3, sl = c & 7;
    const int gch = sl ^ (row & 7);            // un-swizzle via permuted dst chunk
    *(half8*)(O + (size_t)(m0 + row) * 768 + h * 64 + gch * 8) =
        *(const half8*)&sK[row * 64 + sl * 8];
  }
}

// --------------------------- K3: gemm_bt64 (8-wave BK=64, round-9 structure)
// C(M x 768) f32 = A(M x 768 f16) @ B(768 x 768 f16)^T + bias
// 128x128 tile, 8 waves (4M x 2N), BK=64, 12 K-tiles, one vmcnt(0)+barrier each.
__global__ __launch_bounds__(512, 4)
void gemm_bt64(const h16* __restrict__ A,
               const h16* __restrict__ B,
               const float* __restrict__ bias,
               float* __restrict__ C,
               int ntiles) {
  __shared__ h16 As0[2][8192];   // [128][64] swizzled x2
  __shared__ h16 Bs0[2][8192];

  const int nwg = gridDim.x;
  const int bid = blockIdx.x;
  const int wg  = (bid & 7) * (nwg >> 3) + (bid >> 3);
  const int mt = wg / ntiles, nt = wg - mt * ntiles;
  const int m0 = mt * 128, n0 = nt * 128;

  const int tid  = threadIdx.x;
  const int lane = tid & 63;
  const int wv   = tid >> 6;       // 0..7
  const int l16  = lane & 15;
  const int kg   = lane >> 4;
  const int wr   = wv & 3;         // M quarter (rows wr*32, 2 frags)
  const int wc   = wv >> 2;        // N half   (cols wc*64, 4 frags)

  // ---- staging: thread covers chunk (row = i*64 + tid>>3, slot = tid&7)
  const int srow = tid >> 3;
  const int slot = tid & 7;
  const int cg   = slot ^ (srow & 7);
  const h16* pA[2];
  const h16* pB[2];
  int lo[2];
  #pragma unroll
  for (int i = 0; i < 2; ++i) {
    const int r = i * 64 + srow;                 // 0..127
    pA[i] = A + (size_t)(m0 + r) * 768 + cg * 8;
    pB[i] = B + (size_t)(n0 + r) * 768 + cg * 8;
    lo[i] = r * 64 + slot * 8;
  }

#define GLDS(srcp, ldsp)                                                       \
  __builtin_amdgcn_global_load_lds((ga_u32*)(const void*)(srcp),               \
                                   (ls_u32*)(void*)(ldsp), 16, 0, 0)
#define STAGE(bf, kt)                                                          \
  do {                                                                         \
    GLDS(pA[0] + (kt) * 64, &As0[bf][lo[0]]);                                  \
    GLDS(pA[1] + (kt) * 64, &As0[bf][lo[1]]);                                  \
    GLDS(pB[0] + (kt) * 64, &Bs0[bf][lo[0]]);                                  \
    GLDS(pB[1] + (kt) * 64, &Bs0[bf][lo[1]]);                                  \
  } while (0)

  const int aBase = (wr * 32 + l16) * 64;     // + mi*1024 + axor[ks]
  const int bBase = (wc * 64 + l16) * 64;     // + ni*1024 + axor[ks]
  int axor[2];
  #pragma unroll
  for (int ks = 0; ks < 2; ++ks)
    axor[ks] = ((ks * 4 + kg) ^ (l16 & 7)) * 8;

  f32x4 acc[2][4];
  #pragma unroll
  for (int mi = 0; mi < 2; ++mi)
    #pragma unroll
    for (int ni = 0; ni < 4; ++ni)
      acc[mi][ni] = (f32x4){0.f, 0.f, 0.f, 0.f};

  STAGE(0, 0);
  asm volatile("s_waitcnt vmcnt(0)" ::: "memory");
  __syncthreads();

  int cur = 0;
  for (int t = 0; t < 12; ++t) {
    if (t < 11) STAGE(cur ^ 1, t + 1);
    #pragma unroll
    for (int ks = 0; ks < 2; ++ks) {
      half8 af[2], bf8[4];
      #pragma unroll
      for (int mi = 0; mi < 2; ++mi)
        af[mi] = *(const half8*)&As0[cur][aBase + mi * 1024 + axor[ks]];
      #pragma unroll
      for (int ni = 0; ni < 4; ++ni)
        bf8[ni] = *(const half8*)&Bs0[cur][bBase + ni * 1024 + axor[ks]];
      #pragma unroll
      for (int mi = 0; mi < 2; ++mi)
        #pragma unroll
        for (int ni = 0; ni < 4; ++ni)
          acc[mi][ni] = __builtin_amdgcn_mfma_f32_16x16x32_f16(af[mi], bf8[ni], acc[mi][ni], 0, 0, 0);
    }
    asm volatile("s_waitcnt vmcnt(0)" ::: "memory");
    __syncthreads();
    cur ^= 1;
  }
#undef STAGE
#undef GLDS

  float bv[4];
  #pragma unroll
  for (int ni = 0; ni < 4; ++ni) bv[ni] = bias[n0 + wc * 64 + ni * 16 + l16];
  #pragma unroll
  for (int mi = 0; mi < 2; ++mi) {
    #pragma unroll
    for (int ni = 0; ni < 4; ++ni) {
      const int col = n0 + wc * 64 + ni * 16 + l16;
      #pragma unroll
      for (int j = 0; j < 4; ++j) {
        const int row = m0 + wr * 32 + mi * 16 + kg * 4 + j;
        C[(size_t)row * 768 + col] = acc[mi][ni][j] + bv[ni];
      }
    }
  }
}

// ------------------------------------------- fallback: fused kernel (small ws)
template <typename WT>
__device__ __forceinline__ half8 loadw8(const WT* p);
template <>
__device__ __forceinline__ half8 loadw8<h16>(const h16* p) { return *(const half8*)p; }
template <>
__device__ __forceinline__ half8 loadw8<float>(const float* p) {
  const float4 a = *(const float4*)p;
  const float4 b = *(const float4*)(p + 4);
  half8 r;
  r[0] = (h16)a.x; r[1] = (h16)a.y; r[2] = (h16)a.z; r[3] = (h16)a.w;
  r[4] = (h16)b.x; r[5] = (h16)b.y; r[6] = (h16)b.z; r[7] = (h16)b.w;
  return r;
}

template <typename WT>
__launch_bounds__(512, 2)
__global__ void fused_fb(const float* __restrict__ x,
                         const WT* __restrict__ wq,
                         const WT* __restrict__ wp,
                         const float* __restrict__ bias,
                         float* __restrict__ out) {
  __shared__ h16   xs[64][776];
  __shared__ h16   qs[64][72];
  __shared__ h16   ks[64][72];
  __shared__ h16   vt[64][72];
  __shared__ float sS[64][68];

  const int g = blockIdx.x, tid = threadIdx.x;
  const int wv = tid >> 6, lane = tid & 63, l16 = lane & 15, kg = lane >> 4;

  const float* xg = x + (size_t)g * (64 * 768);
  #pragma unroll
  for (int i = 0; i < 24; ++i) {
    const int idx = tid + i * 512;
    const int row = idx / 192;
    const int c4  = (idx - row * 192) * 4;
    const float4 v = ((const float4*)xg)[idx];
    h16* p = &xs[row][c4];
    p[0] = (h16)v.x; p[1] = (h16)v.y; p[2] = (h16)v.z; p[3] = (h16)v.w;
  }

  f32x4 acc[4][6];
  #pragma unroll
  for (int a = 0; a < 4; ++a)
    #pragma unroll
    for (int b = 0; b < 6; ++b) acc[a][b] = (f32x4){0.f, 0.f, 0.f, 0.f};

  float bcol[6];
  #pragma unroll
  for (int cb = 0; cb < 6; ++cb) bcol[cb] = bias[wv * 96 + cb * 16 + l16];

  const int r0 = (wv & 1) * 32, c0 = (wv >> 1) * 48;
  const int rS = (wv >> 1) * 16, cS = (wv & 1) * 32;
  __syncthreads();

  for (int h = 0; h < 12; ++h) {
    f32x4 facc[2][3];
    #pragma unroll
    for (int a = 0; a < 2; ++a)
      #pragma unroll
      for (int b = 0; b < 3; ++b) facc[a][b] = (f32x4){0.f, 0.f, 0.f, 0.f};
    int wrow[3];
    #pragma unroll
    for (int cb = 0; cb < 3; ++cb) {
      const int n = c0 + cb * 16;
      wrow[cb] = (n >> 6) * 768 + h * 64 + (n & 63) + l16;
    }
    for (int k0 = 0; k0 < 768; k0 += 32) {
      const half8 a0 = *(const half8*)&xs[r0 + l16][k0 + kg * 8];
      const half8 a1 = *(const half8*)&xs[r0 + 16 + l16][k0 + kg * 8];
      #pragma unroll
      for (int cb = 0; cb < 3; ++cb) {
        const half8 b = loadw8<WT>(wq + (size_t)wrow[cb] * 768 + k0 + kg * 8);
        facc[0][cb] = __builtin_amdgcn_mfma_f32_16x16x32_f16(a0, b, facc[0][cb], 0, 0, 0);
        facc[1][cb] = __builtin_amdgcn_mfma_f32_16x16x32_f16(a1, b, facc[1][cb], 0, 0, 0);
      }
    }
    #pragma unroll
    for (int rb = 0; rb < 2; ++rb)
      #pragma unroll
      for (int cb = 0; cb < 3; ++cb) {
        const int col = c0 + cb * 16 + l16;
        const int rowb = r0 + rb * 16 + kg * 4;
        if (col < 64) {
          #pragma unroll
          for (int j = 0; j < 4; ++j) qs[rowb + j][col] = (h16)facc[rb][cb][j];
        } else if (col < 128) {
          #pragma unroll
          for (int j = 0; j < 4; ++j) ks[rowb + j][col - 64] = (h16)facc[rb][cb][j];
        } else {
          #pragma unroll
          for (int j = 0; j < 4; ++j) vt[col - 128][rowb + j] = (h16)facc[rb][cb][j];
        }
      }
    __syncthreads();

    f32x4 sacc[2];
    sacc[0] = (f32x4){0.f, 0.f, 0.f, 0.f};
    sacc[1] = (f32x4){0.f, 0.f, 0.f, 0.f};
    #pragma unroll
    for (int k0 = 0; k0 < 64; k0 += 32) {
      const half8 aq = *(const half8*)&qs[rS + l16][k0 + kg * 8];
      const half8 b0 = *(const half8*)&ks[cS + l16][k0 + kg * 8];
      const half8 b1 = *(const half8*)&ks[cS + 16 + l16][k0 + kg * 8];
      sacc[0] = __builtin_amdgcn_mfma_f32_16x16x32_f16(aq, b0, sacc[0], 0, 0, 0);
      sacc[1] = __builtin_amdgcn_mfma_f32_16x16x32_f16(aq, b1, sacc[1], 0, 0, 0);
    }
    #pragma unroll
    for (int t = 0; t < 2; ++t)
      #pragma unroll
      for (int j = 0; j < 4; ++j)
        sS[rS + kg * 4 + j][cS + t * 16 + l16] = sacc[t][j] * SCALE;
    __syncthreads();

    {
      const int row = tid >> 3, j0 = (tid & 7) * 8;
      float v0[8];
      #pragma unroll
      for (int i = 0; i < 8; ++i) v0[i] = sS[row][j0 + i];
      float m = v0[0];
      #pragma unroll
      for (int i = 1; i < 8; ++i) m = fmaxf(m, v0[i]);
      m = fmaxf(m, __shfl_xor(m, 1));
      m = fmaxf(m, __shfl_xor(m, 2));
      m = fmaxf(m, __shfl_xor(m, 4));
      float e[8], ssum = 0.f;
      #pragma unroll
      for (int i = 0; i < 8; ++i) { e[i] = __expf(v0[i] - m); ssum += e[i]; }
      ssum += __shfl_xor(ssum, 1);
      ssum += __shfl_xor(ssum, 2);
      ssum += __shfl_xor(ssum, 4);
      const float inv = 1.0f / ssum;
      #pragma unroll
      for (int i = 0; i < 8; ++i) qs[row][j0 + i] = (h16)(e[i] * inv);
    }
    __syncthreads();

    f32x4 oacc[2];
    oacc[0] = (f32x4){0.f, 0.f, 0.f, 0.f};
    oacc[1] = (f32x4){0.f, 0.f, 0.f, 0.f};
    #pragma unroll
    for (int k0 = 0; k0 < 64; k0 += 32) {
      const half8 ap = *(const half8*)&qs[rS + l16][k0 + kg * 8];
      const half8 b0 = *(const half8*)&vt[cS + l16][k0 + kg * 8];
      const half8 b1 = *(const half8*)&vt[cS + 16 + l16][k0 + kg * 8];
      oacc[0] = __builtin_amdgcn_mfma_f32_16x16x32_f16(ap, b0, oacc[0], 0, 0, 0);
      oacc[1] = __builtin_amdgcn_mfma_f32_16x16x32_f16(ap, b1, oacc[1], 0, 0, 0);
    }
    #pragma unroll
    for (int t = 0; t < 2; ++t)
      #pragma unroll
      for (int j = 0; j < 4; ++j)
        ks[rS + kg * 4 + j][cS + t * 16 + l16] = (h16)oacc[t][j];
    __syncthreads();

    #pragma unroll
    for (int k0 = 0; k0 < 64; k0 += 32) {
      half8 ah[4];
      #pragma unroll
      for (int rb = 0; rb < 4; ++rb)
        ah[rb] = *(const half8*)&ks[rb * 16 + l16][k0 + kg * 8];
      #pragma unroll
      for (int cb = 0; cb < 6; ++cb) {
        const int ocol = wv * 96 + cb * 16 + l16;
        const half8 bw = loadw8<WT>(wp + (size_t)ocol * 768 + h * 64 + k0 + kg * 8);
        #pragma unroll
        for (int rb = 0; rb < 4; ++rb)
          acc[rb][cb] = __builtin_amdgcn_mfma_f32_16x16x32_f16(ah[rb], bw, acc[rb][cb], 0, 0, 0);
      }
    }
    __syncthreads();
  }

  float* og = out + (size_t)g * (64 * 768);
  #pragma unroll
  for (int rb = 0; rb < 4; ++rb)
    #pragma unroll
    for (int cb = 0; cb < 6; ++cb) {
      const int col = wv * 96 + cb * 16 + l16;
      #pragma unroll
      for (int j = 0; j < 4; ++j) {
        const int row = rb * 16 + kg * 4 + j;
        og[(size_t)row * 768 + col] = acc[rb][cb][j] + bcol[cb];
      }
    }
}

// ---------------------------------------------------------------- launch
extern "C" void kernel_launch(void* const* d_in, const int* in_sizes, int n_in,
                              void* d_out, int out_size, void* d_ws, size_t ws_size,
                              hipStream_t stream) {
  const float* x     = (const float*)d_in[0];
  const float* wqkv  = (const float*)d_in[1];
  const float* wproj = (const float*)d_in[2];
  const float* bias  = (const float*)d_in[3];
  float* out = (float*)d_out;

  const size_t SZ_WQ = (size_t)2304 * 768 * sizeof(h16);   //   3.54 MB
  const size_t SZ_WP = (size_t)768 * 768 * sizeof(h16);    //   1.18 MB
  const size_t SZ_XH = (size_t)65536 * 768 * sizeof(h16);  // 100.66 MB
  const size_t SZ_O  = (size_t)65536 * 768 * sizeof(h16);  // 100.66 MB

  if (ws_size >= SZ_WQ + SZ_WP + SZ_XH + SZ_O) {
    h16* wq16 = (h16*)d_ws;
    h16* wp16 = (h16*)((char*)d_ws + SZ_WQ);
    h16* xh   = (h16*)((char*)d_ws + SZ_WQ + SZ_WP);
    h16* obuf = (h16*)((char*)d_ws + SZ_WQ + SZ_WP + SZ_XH);

    prep_cvt<<<2048, 256, 0, stream>>>(wqkv, wproj, x, wq16, wp16, xh);
    qkv_attn<<<6144, 512, 0, stream>>>(xh, wq16, obuf);
    gemm_bt64<<<3072, 512, 0, stream>>>(obuf, wp16, bias, out, 6);
  } else if (ws_size >= SZ_WQ + SZ_WP) {
    h16* wq16 = (h16*)d_ws;
    h16* wp16 = (h16*)((char*)d_ws + SZ_WQ);
    prep_w_only<<<512, 256, 0, stream>>>(wqkv, wproj, wq16, wp16);
    fused_fb<h16><<<1024, 512, 0, stream>>>(x, wq16, wp16, bias, out);
  } else {
    fused_fb<float><<<1024, 512, 0, stream>>>(x, wqkv, wproj, bias, out);
  }
}